// Round 11
// baseline (317.300 us; speedup 1.0000x reference)
//
#include <hip/hip_runtime.h>
#include <math.h>

#define NTOT 32768   // B*NP
#define NPG  4096    // nodes per graph
#define BGR  8       // graphs
#define KK   1024    // top-k
#define NN   8192    // B*K kept nodes
#define NE   262144  // edges

typedef __attribute__((ext_vector_type(8))) short bf16x8;
typedef __attribute__((ext_vector_type(4))) float f32x4;

static __device__ __forceinline__ unsigned short f2bf(float f) {
    unsigned u = __float_as_uint(f);
    return (unsigned short)((u + 0x7fffu + ((u >> 16) & 1u)) >> 16);
}
static __device__ __forceinline__ float bf2f(unsigned short b) {
    return __uint_as_float(((unsigned)b) << 16);
}

// ---------------- top-k per graph: radix select + ordered compaction ----------------
// Also initializes remap (all 4096 nodes of its graph) and zeroes deg/cursor slice.
__global__ __launch_bounds__(1024) void k_topk2(const float* __restrict__ pos,
                                                const float* __restrict__ p,
                                                int* __restrict__ remap,
                                                float* __restrict__ x0f,
                                                unsigned short* __restrict__ Ab0,
                                                int* __restrict__ deg,
                                                int* __restrict__ cursor) {
    __shared__ unsigned skey[NPG];
    __shared__ float sval[NPG];
    __shared__ int hist[256];
    __shared__ int Sarr[256];
    __shared__ int wsum[16];
    __shared__ int s_bin, s_above;

    const int g = blockIdx.x, tid = threadIdx.x;
    const int lane = tid & 63, wid = tid >> 6;
    deg[g * KK + tid] = 0;
    cursor[g * KK + tid] = 0;
    const float p0 = p[0], p1 = p[1], p2 = p[2];
    const float invn = 1.0f / sqrtf(p0 * p0 + p1 * p1 + p2 * p2);

    for (int i = tid; i < NPG; i += 1024) {
        const float* pp = pos + (size_t)(g * NPG + i) * 3;
        float s = tanhf((pp[0] * p0 + pp[1] * p1 + pp[2] * p2) * invn);
        sval[i] = s;
        unsigned b = __float_as_uint(s);
        skey[i] = (b & 0x80000000u) ? ~b : (b | 0x80000000u);
    }
    __syncthreads();

    unsigned prefix = 0;
    int needed = KK;
    for (int r = 0; r < 4; ++r) {
        const int sh = 24 - 8 * r;
        if (tid < 256) hist[tid] = 0;
        __syncthreads();
        for (int i = tid; i < NPG; i += 1024) {
            unsigned k = skey[i];
            bool act = (r == 0) || ((k >> (sh + 8)) == prefix);
            if (act) atomicAdd(&hist[(k >> sh) & 255u], 1);
        }
        __syncthreads();
        if (wid == 0) {
            int h0 = hist[4 * lane + 0], h1 = hist[4 * lane + 1];
            int h2 = hist[4 * lane + 2], h3 = hist[4 * lane + 3];
            int l3 = h3, l2 = h2 + l3, l1 = h1 + l2, l0 = h0 + l1;
            int t = l0;
            for (int off = 1; off < 64; off <<= 1) {
                int n = __shfl_down(t, off, 64);
                if (lane + off < 64) t += n;
            }
            int hi = t - l0;
            Sarr[4 * lane + 0] = l0 + hi;
            Sarr[4 * lane + 1] = l1 + hi;
            Sarr[4 * lane + 2] = l2 + hi;
            Sarr[4 * lane + 3] = l3 + hi;
        }
        __syncthreads();
        if (tid < 256) {
            int Sb = Sarr[tid];
            int Sb1 = (tid < 255) ? Sarr[tid + 1] : 0;
            if (Sb >= needed && Sb1 < needed) { s_bin = tid; s_above = Sb1; }
        }
        __syncthreads();
        needed -= s_above;
        prefix = (prefix << 8) | (unsigned)s_bin;
        __syncthreads();
    }
    const unsigned Tkey = prefix;
    const int needTies = needed;

    int tiebase = 0, keepbase = 0;
    for (int c = 0; c < 4; ++c) {
        const int i = c * 1024 + tid;
        const unsigned k = skey[i];
        const int tie = (k == Tkey) ? 1 : 0;
        int v = tie;
        for (int off = 1; off < 64; off <<= 1) {
            int n = __shfl_up(v, off, 64);
            if (lane >= off) v += n;
        }
        if (lane == 63) wsum[wid] = v;
        __syncthreads();
        if (wid == 0) {
            int w = (lane < 16) ? wsum[lane] : 0;
            for (int off = 1; off < 16; off <<= 1) {
                int n = __shfl_up(w, off, 64);
                if (lane >= off) w += n;
            }
            if (lane < 16) wsum[lane] = w;
        }
        __syncthreads();
        const int trank = tiebase + v + (wid > 0 ? wsum[wid - 1] : 0) - tie;
        const int ttot = wsum[15];
        const int keep = (k > Tkey) || (tie && trank < needTies);
        __syncthreads();
        int u = keep;
        for (int off = 1; off < 64; off <<= 1) {
            int n = __shfl_up(u, off, 64);
            if (lane >= off) u += n;
        }
        if (lane == 63) wsum[wid] = u;
        __syncthreads();
        if (wid == 0) {
            int w = (lane < 16) ? wsum[lane] : 0;
            for (int off = 1; off < 16; off <<= 1) {
                int n = __shfl_up(w, off, 64);
                if (lane >= off) w += n;
            }
            if (lane < 16) wsum[lane] = w;
        }
        __syncthreads();
        const int kincl = u + (wid > 0 ? wsum[wid - 1] : 0);
        const int ktot = wsum[15];
        if (keep) {
            int nn = g * KK + keepbase + kincl - 1;
            remap[g * NPG + i] = nn;
            float val = sval[i];
            const float* pp = pos + (size_t)(g * NPG + i) * 3;
            float v0 = pp[0] * val, v1 = pp[1] * val, v2 = pp[2] * val;
            x0f[(size_t)nn * 3 + 0] = v0;
            x0f[(size_t)nn * 3 + 1] = v1;
            x0f[(size_t)nn * 3 + 2] = v2;
            unsigned short* rw = Ab0 + (size_t)nn * 32;
            ushort4 a = make_ushort4(f2bf(v0), f2bf(v1), f2bf(v2), 0);
            ushort4 z = make_ushort4(0, 0, 0, 0);
            *(ushort4*)(rw) = a;
#pragma unroll
            for (int t = 1; t < 8; ++t) *(ushort4*)(rw + 4 * t) = z;
        } else {
            remap[g * NPG + i] = -1;
        }
        tiebase += ttot;
        keepbase += ktot;
        __syncthreads();
    }
}

// ---------------- pass 1: in-degree (+ zero the 5-layer BN stat accumulators) ----------------
__global__ void k_deg(const int* __restrict__ ei, const int* __restrict__ remap,
                      int* __restrict__ deg, float* __restrict__ gstatAll) {
    int e = blockIdx.x * blockDim.x + threadIdx.x;
    if (e < 5 * 1024) gstatAll[e] = 0.0f;
    if (e >= NE) return;
    int s = remap[ei[e]];
    int d = remap[ei[NE + e]];
    if (s >= 0 && d >= 0) atomicAdd(&deg[d], 1);
}

// ---------------- exclusive scan of deg -> rowptr ----------------
__global__ __launch_bounds__(1024) void k_scan(const int* __restrict__ deg,
                                               int* __restrict__ rowptr) {
    __shared__ int part[1024];
    const int tid = threadIdx.x;
    const int base = tid * 8;
    int loc[8];
    int s = 0;
#pragma unroll
    for (int i = 0; i < 8; ++i) { loc[i] = s; s += deg[base + i]; }
    part[tid] = s;
    __syncthreads();
    for (int off = 1; off < 1024; off <<= 1) {
        int v = (tid >= off) ? part[tid - off] : 0;
        __syncthreads();
        part[tid] += v;
        __syncthreads();
    }
    int pre = (tid > 0) ? part[tid - 1] : 0;
#pragma unroll
    for (int i = 0; i < 8; ++i) rowptr[base + i] = pre + loc[i];
    if (tid == 1023) rowptr[NN] = pre + s;
}

// ---------------- pass 2: place edges into CSR (by dst) ----------------
__global__ void k_place2(const int* __restrict__ ei, const int* __restrict__ remap,
                         const int* __restrict__ deg, const int* __restrict__ rowptr,
                         int* __restrict__ cursor, int* __restrict__ col,
                         float* __restrict__ ew) {
    int e = blockIdx.x * blockDim.x + threadIdx.x;
    if (e >= NE) return;
    int s = remap[ei[e]];
    int d = remap[ei[NE + e]];
    if (s >= 0 && d >= 0) {
        int pos = rowptr[d] + atomicAdd(&cursor[d], 1);
        col[pos] = s;
        ew[pos] = rsqrtf((float)(deg[s] + 1)) * rsqrtf((float)(deg[d] + 1));
    }
}

// ---------------- all weights transpose + bf16 convert, one launch ----------------
__global__ void k_wt_all(const float* __restrict__ w0, const float* __restrict__ w1,
                         const float* __restrict__ w2, const float* __restrict__ w3,
                         const float* __restrict__ w4,
                         unsigned short* __restrict__ t0, unsigned short* __restrict__ t1,
                         unsigned short* __restrict__ t2, unsigned short* __restrict__ t3,
                         unsigned short* __restrict__ t4) {
    int i = blockIdx.x * blockDim.x + threadIdx.x;
    const float* W; unsigned short* T; int Kd, Nc, Kpad, base;
    if (i < 2048)        { W = w0; T = t0; Kd = 3;   Nc = 64;  Kpad = 32;  base = 0; }
    else if (i < 10240)  { W = w1; T = t1; Kd = 64;  Nc = 128; Kpad = 64;  base = 2048; }
    else if (i < 26624)  { W = w2; T = t2; Kd = 128; Nc = 128; Kpad = 128; base = 10240; }
    else if (i < 59392)  { W = w3; T = t3; Kd = 128; Nc = 256; Kpad = 128; base = 26624; }
    else if (i < 190464) { W = w4; T = t4; Kd = 256; Nc = 512; Kpad = 256; base = 59392; }
    else return;
    int j = i - base;
    int n = j / Kpad, k = j - n * Kpad;
    float v = (k < Kd) ? W[(size_t)k * Nc + n] : 0.0f;
    T[j] = f2bf(v);
}

// ---------------- MFMA bf16 GEMM: Hb = bf16(A @ W), A staged ONCE in LDS ----------------
// A source: bf16 Ab0 (l=0) or f32 Yin with fused BN(from gstat)+relu+bf16 (l>=1).
// Block: 64 rows x ALL Nc cols (col-tile loop). 4 waves; wave = 32x32 per col tile.
#define KPAD_MAX 264
__global__ __launch_bounds__(256) void k_mm2(const unsigned short* __restrict__ Ab0,
                                             const float* __restrict__ Yin,
                                             const float* __restrict__ gstat,
                                             const float* __restrict__ gamma,
                                             const float* __restrict__ beta,
                                             const unsigned short* __restrict__ WT,
                                             unsigned short* __restrict__ Hb,
                                             int Kd, int Nc) {
    __shared__ unsigned short As[64 * KPAD_MAX];
    __shared__ float sc_s[256], sh_s[256];
    const int tid = threadIdx.x;
    const int bm = blockIdx.x * 64;
    const int KP = Kd + 8;
    const int QK = Kd >> 2;
    if (Yin) {
        for (int c = tid; c < Kd; c += 256) {
            double mean = (double)gstat[c] / 8192.0;
            double var = (double)gstat[512 + c] / 8192.0 - mean * mean;
            float sc = (float)((double)gamma[c] / sqrt(var + 1e-5));
            sc_s[c] = sc;
            sh_s[c] = beta[c] - (float)mean * sc;
        }
        __syncthreads();
        for (int idx = tid; idx < 64 * QK; idx += 256) {
            int row = idx / QK, q = idx - row * QK;
            float4 v = *(const float4*)&Yin[(size_t)(bm + row) * Kd + 4 * q];
            float4 sc = *(const float4*)&sc_s[4 * q];
            float4 sh = *(const float4*)&sh_s[4 * q];
            ushort4 o;
            o.x = f2bf(fmaxf(v.x * sc.x + sh.x, 0.0f));
            o.y = f2bf(fmaxf(v.y * sc.y + sh.y, 0.0f));
            o.z = f2bf(fmaxf(v.z * sc.z + sh.z, 0.0f));
            o.w = f2bf(fmaxf(v.w * sc.w + sh.w, 0.0f));
            *(ushort4*)&As[row * KP + 4 * q] = o;
        }
    } else {
        for (int idx = tid; idx < 64 * QK; idx += 256) {
            int row = idx / QK, q = idx - row * QK;
            *(ushort4*)&As[row * KP + 4 * q] =
                *(const ushort4*)&Ab0[(size_t)(bm + row) * Kd + 4 * q];
        }
    }
    __syncthreads();

    const int lane = tid & 63, wid = tid >> 6;
    const int rloc = (wid >> 1) * 32;
    const int cloc = (wid & 1) * 32;
    const int fr = lane & 15;
    const int ko = (lane >> 4) << 3;
    const unsigned short* A0 = &As[(rloc + fr) * KP + ko];
    const int strA = 16 * KP;
    const size_t strB = (size_t)16 * Kd;
    const int r = lane & 15;
    const int c4 = (lane >> 4) << 2;

    for (int ct = 0; ct < Nc; ct += 64) {
        const unsigned short* B0 = WT + (size_t)(ct + cloc + fr) * Kd + ko;
        f32x4 acc00 = {0,0,0,0}, acc01 = {0,0,0,0}, acc10 = {0,0,0,0}, acc11 = {0,0,0,0};
        for (int k0 = 0; k0 < Kd; k0 += 32) {
            bf16x8 a0 = *(const bf16x8*)(A0 + k0);
            bf16x8 a1 = *(const bf16x8*)(A0 + strA + k0);
            bf16x8 b0 = *(const bf16x8*)(B0 + k0);
            bf16x8 b1 = *(const bf16x8*)(B0 + strB + k0);
            acc00 = __builtin_amdgcn_mfma_f32_16x16x32_bf16(b0, a0, acc00, 0, 0, 0);
            acc01 = __builtin_amdgcn_mfma_f32_16x16x32_bf16(b1, a0, acc01, 0, 0, 0);
            acc10 = __builtin_amdgcn_mfma_f32_16x16x32_bf16(b0, a1, acc10, 0, 0, 0);
            acc11 = __builtin_amdgcn_mfma_f32_16x16x32_bf16(b1, a1, acc11, 0, 0, 0);
        }
#pragma unroll
        for (int tm = 0; tm < 2; ++tm) {
            const int row = bm + rloc + tm * 16 + r;
            const size_t basep = (size_t)row * Nc;
            const f32x4 aL = tm ? acc10 : acc00;
            const f32x4 aR = tm ? acc11 : acc01;
#pragma unroll
            for (int tn = 0; tn < 2; ++tn) {
                const f32x4 a = tn ? aR : aL;
                const int c = ct + cloc + tn * 16 + c4;
                *(ushort4*)&Hb[basep + c] = make_ushort4(f2bf(a[0]), f2bf(a[1]),
                                                         f2bf(a[2]), f2bf(a[3]));
            }
        }
    }
}

// ---------------- f32 fallback matmul ----------------
#define BM 64
#define BNT 64
#define BKT 16
__global__ __launch_bounds__(256) void k_mm(const float* __restrict__ A,
                                            const float* __restrict__ W,
                                            float* __restrict__ H, int Kd, int Nc) {
    __shared__ float As[BM][BKT + 1];
    __shared__ float Bs[BKT][BNT + 1];
    const int bm = blockIdx.x * BM;
    const int bn = blockIdx.y * BNT;
    const int tid = threadIdx.x;
    const int tx = tid & 15, ty = tid >> 4;
    float acc[4][4] = {};
    for (int k0 = 0; k0 < Kd; k0 += BKT) {
        for (int t = 0; t < 4; ++t) {
            int i = tid + t * 256;
            int m = i >> 4, k = i & 15;
            As[m][k] = (k0 + k < Kd) ? A[(size_t)(bm + m) * Kd + k0 + k] : 0.0f;
        }
        for (int t = 0; t < 4; ++t) {
            int i = tid + t * 256;
            int k = i >> 6, n = i & 63;
            Bs[k][n] = (k0 + k < Kd) ? W[(size_t)(k0 + k) * Nc + bn + n] : 0.0f;
        }
        __syncthreads();
        for (int k = 0; k < BKT; ++k) {
            float a[4], b[4];
#pragma unroll
            for (int i = 0; i < 4; ++i) a[i] = As[ty * 4 + i][k];
#pragma unroll
            for (int j = 0; j < 4; ++j) b[j] = Bs[k][tx * 4 + j];
#pragma unroll
            for (int i = 0; i < 4; ++i)
#pragma unroll
                for (int j = 0; j < 4; ++j) acc[i][j] += a[i] * b[j];
        }
        __syncthreads();
    }
#pragma unroll
    for (int i = 0; i < 4; ++i)
        *(float4*)&H[(size_t)(bm + ty * 4 + i) * Nc + bn + tx * 4] =
            make_float4(acc[i][0], acc[i][1], acc[i][2], acc[i][3]);
}

// ---------------- fused: Y = H*inv + bias + CSR-gather; BN stats via atomics ----------------
// block = (32-row chunk) x (64-channel slab). gstat: [0:512)=sum, [512:1024)=sumsq.
#define BN1_ROWS 32
#define BN1_CHUNKS (NN / BN1_ROWS)   // 256
__global__ __launch_bounds__(256) void k_gfuse(const unsigned short* __restrict__ Hb,
                                               const float* __restrict__ Hf,
                                               const int* __restrict__ rowptr,
                                               const int* __restrict__ col,
                                               const float* __restrict__ ew,
                                               const int* __restrict__ deg,
                                               const float* __restrict__ bias,
                                               float* __restrict__ Y,
                                               float* __restrict__ gstat, int Nc) {
    __shared__ float4 ls[256], lq[256];
    const int CB = Nc >> 6;
    const int chunk = blockIdx.x / CB;
    const int cb = blockIdx.x - chunk * CB;
    const int tid = threadIdx.x;
    const int q = tid & 15;
    const int rg = tid >> 4;
    const int c = cb * 64 + (q << 2);
    const float4 b4 = *(const float4*)&bias[c];
    float4 s4 = make_float4(0, 0, 0, 0), q4 = make_float4(0, 0, 0, 0);
#pragma unroll
    for (int rr = 0; rr < 2; ++rr) {
        const int n = chunk * BN1_ROWS + rg * 2 + rr;
        const int j0 = rowptr[n], j1 = rowptr[n + 1];
        const float inv = 1.0f / (float)(deg[n] + 1);
        float4 acc;
        if (Hb) {
            ushort4 hv = *(const ushort4*)&Hb[(size_t)n * Nc + c];
            acc = make_float4(bf2f(hv.x), bf2f(hv.y), bf2f(hv.z), bf2f(hv.w));
        } else {
            acc = *(const float4*)&Hf[(size_t)n * Nc + c];
        }
        acc.x = acc.x * inv + b4.x;
        acc.y = acc.y * inv + b4.y;
        acc.z = acc.z * inv + b4.z;
        acc.w = acc.w * inv + b4.w;
        if (Hb) {
            for (int j = j0; j < j1; ++j) {
                const float w = ew[j];
                ushort4 hv = *(const ushort4*)&Hb[(size_t)col[j] * Nc + c];
                acc.x += bf2f(hv.x) * w; acc.y += bf2f(hv.y) * w;
                acc.z += bf2f(hv.z) * w; acc.w += bf2f(hv.w) * w;
            }
        } else {
            for (int j = j0; j < j1; ++j) {
                const float w = ew[j];
                const float4 hv = *(const float4*)&Hf[(size_t)col[j] * Nc + c];
                acc.x += hv.x * w; acc.y += hv.y * w; acc.z += hv.z * w; acc.w += hv.w * w;
            }
        }
        *(float4*)&Y[(size_t)n * Nc + c] = acc;
        s4.x += acc.x; s4.y += acc.y; s4.z += acc.z; s4.w += acc.w;
        q4.x += acc.x * acc.x; q4.y += acc.y * acc.y;
        q4.z += acc.z * acc.z; q4.w += acc.w * acc.w;
    }
    ls[tid] = s4; lq[tid] = q4;
    __syncthreads();
    for (int st = 128; st >= 16; st >>= 1) {
        if (tid < st) {
            float4 a = ls[tid], b = ls[tid + st];
            ls[tid] = make_float4(a.x + b.x, a.y + b.y, a.z + b.z, a.w + b.w);
            float4 e = lq[tid], f = lq[tid + st];
            lq[tid] = make_float4(e.x + f.x, e.y + f.y, e.z + f.z, e.w + f.w);
        }
        __syncthreads();
    }
    if (tid < 16) {
        float4 a = ls[tid], b = lq[tid];
        atomicAdd(&gstat[c + 0], a.x); atomicAdd(&gstat[c + 1], a.y);
        atomicAdd(&gstat[c + 2], a.z); atomicAdd(&gstat[c + 3], a.w);
        atomicAdd(&gstat[512 + c + 0], b.x); atomicAdd(&gstat[512 + c + 1], b.y);
        atomicAdd(&gstat[512 + c + 2], b.z); atomicAdd(&gstat[512 + c + 3], b.w);
    }
}

// f32 fallback bn-apply (scale/shift from gstat inline)
__global__ void k_bnapply(float* x, const float* __restrict__ gstat,
                          const float* __restrict__ gamma, const float* __restrict__ beta,
                          int Nc) {
    int i = blockIdx.x * blockDim.x + threadIdx.x;
    int c0 = (i & ((Nc >> 2) - 1)) << 2;
    float4 v = ((const float4*)x)[i];
    float r[4] = {v.x, v.y, v.z, v.w};
#pragma unroll
    for (int k = 0; k < 4; ++k) {
        int c = c0 + k;
        double mean = (double)gstat[c] / 8192.0;
        double var = (double)gstat[512 + c] / 8192.0 - mean * mean;
        float sc = (float)((double)gamma[c] / sqrt(var + 1e-5));
        float sh = beta[c] - (float)mean * sc;
        r[k] = fmaxf(r[k] * sc + sh, 0.0f);
    }
    ((float4*)x)[i] = make_float4(r[0], r[1], r[2], r[3]);
}

// ---------------- pool stage A with fused BN+relu (reads Y f32, stats from gstat) ----------------
#define PR 32
__global__ __launch_bounds__(256) void k_pool_af(const float* __restrict__ Y,
                                                 const float* __restrict__ gstat,
                                                 const float* __restrict__ gamma,
                                                 const float* __restrict__ beta,
                                                 float* __restrict__ part) {
    __shared__ float4 red[128];
    const int g = blockIdx.x >> 5;
    const int rs = blockIdx.x & 31;
    const int half = threadIdx.x >> 7;
    const int q = threadIdx.x & 127;
    const int c = 4 * q;
    float4 sc, sh;
    {
        double m0 = (double)gstat[c + 0] / 8192.0;
        double v0 = (double)gstat[512 + c + 0] / 8192.0 - m0 * m0;
        sc.x = (float)((double)gamma[c + 0] / sqrt(v0 + 1e-5));
        sh.x = beta[c + 0] - (float)m0 * sc.x;
        double m1 = (double)gstat[c + 1] / 8192.0;
        double v1 = (double)gstat[512 + c + 1] / 8192.0 - m1 * m1;
        sc.y = (float)((double)gamma[c + 1] / sqrt(v1 + 1e-5));
        sh.y = beta[c + 1] - (float)m1 * sc.y;
        double m2 = (double)gstat[c + 2] / 8192.0;
        double v2 = (double)gstat[512 + c + 2] / 8192.0 - m2 * m2;
        sc.z = (float)((double)gamma[c + 2] / sqrt(v2 + 1e-5));
        sh.z = beta[c + 2] - (float)m2 * sc.z;
        double m3 = (double)gstat[c + 3] / 8192.0;
        double v3 = (double)gstat[512 + c + 3] / 8192.0 - m3 * m3;
        sc.w = (float)((double)gamma[c + 3] / sqrt(v3 + 1e-5));
        sh.w = beta[c + 3] - (float)m3 * sc.w;
    }
    const float* xp = Y + (size_t)(g * KK + rs * PR + half * 16) * 512 + c;
    float4 s = make_float4(0, 0, 0, 0);
#pragma unroll
    for (int rr = 0; rr < 16; ++rr) {
        float4 v = *(const float4*)(xp + (size_t)rr * 512);
        s.x += fmaxf(v.x * sc.x + sh.x, 0.0f);
        s.y += fmaxf(v.y * sc.y + sh.y, 0.0f);
        s.z += fmaxf(v.z * sc.z + sh.z, 0.0f);
        s.w += fmaxf(v.w * sc.w + sh.w, 0.0f);
    }
    if (half == 1) red[q] = s;
    __syncthreads();
    if (half == 0) {
        float4 t = red[q];
        s.x += t.x; s.y += t.y; s.z += t.z; s.w += t.w;
        *(float4*)&part[(size_t)blockIdx.x * 512 + c] = s;
    }
}

// f32 fallback pool (x already BN-applied)
__global__ __launch_bounds__(256) void k_pool(const float* __restrict__ x, float* pooled) {
    __shared__ float red[4][64];
    int g = blockIdx.x >> 3;
    int c0 = (blockIdx.x & 7) * 64;
    int c = threadIdx.x & 63;
    int rp = threadIdx.x >> 6;
    float s = 0;
    for (int r = rp; r < KK; r += 4)
        s += x[(size_t)(g * KK + r) * 512 + c0 + c];
    red[rp][c] = s;
    __syncthreads();
    if (rp == 0)
        pooled[g * 512 + c0 + c] = red[0][c] + red[1][c] + red[2][c] + red[3][c];
}

// ---------------- fused pool_b + FC1 + FC2 + FC3 + log_softmax: 8 blocks ----------------
__global__ __launch_bounds__(256) void k_fc123(const float* __restrict__ part,
                                               const float* __restrict__ fw1,
                                               const float* __restrict__ fb1,
                                               const float* __restrict__ fw2,
                                               const float* __restrict__ fb2,
                                               const float* __restrict__ fw3,
                                               const float* __restrict__ fb3,
                                               float* __restrict__ out, int nparts) {
    __shared__ float pooled[512];
    __shared__ float t1s[256];
    __shared__ float t2s[256];
    __shared__ float red[256];
    __shared__ float logits[100];
    const int g = blockIdx.x, tid = threadIdx.x;
    for (int c = tid; c < 512; c += 256) {
        float s = 0;
        for (int i = 0; i < nparts; ++i) s += part[(size_t)(g * nparts + i) * 512 + c];
        pooled[c] = s;
    }
    __syncthreads();
    float a1 = fb1[tid];
    for (int k = 0; k < 512; ++k) a1 += pooled[k] * fw1[k * 256 + tid];
    t1s[tid] = fmaxf(a1, 0.0f);
    __syncthreads();
    float a2 = fb2[tid];
    for (int k = 0; k < 256; ++k) a2 += t1s[k] * fw2[k * 256 + tid];
    t2s[tid] = fmaxf(a2, 0.0f);
    __syncthreads();
    float v = -INFINITY;
    if (tid < 100) {
        float a3 = fb3[tid];
        for (int k = 0; k < 256; ++k) a3 += t2s[k] * fw3[k * 100 + tid];
        logits[tid] = a3;
        v = a3;
    }
    red[tid] = v;
    __syncthreads();
    for (int s = 128; s > 0; s >>= 1) {
        if (tid < s) red[tid] = fmaxf(red[tid], red[tid + s]);
        __syncthreads();
    }
    float mx = red[0];
    __syncthreads();
    red[tid] = (tid < 100) ? expf(logits[tid] - mx) : 0.0f;
    __syncthreads();
    for (int s = 128; s > 0; s >>= 1) {
        if (tid < s) red[tid] += red[tid + s];
        __syncthreads();
    }
    float lse = logf(red[0]);
    if (tid < 100) out[g * 100 + tid] = logits[tid] - mx - lse;
}

// plain FC + relu (fallback path)
__global__ void k_fc(const float* __restrict__ in, const float* __restrict__ W,
                     const float* __restrict__ bias, float* out, int fi, int fo) {
    __shared__ float row[512];
    int g = blockIdx.x, tid = threadIdx.x;
    for (int k = tid; k < fi; k += blockDim.x) row[k] = in[g * fi + k];
    __syncthreads();
    if (tid < fo) {
        float acc = bias[tid];
        for (int k = 0; k < fi; ++k) acc += row[k] * W[k * fo + tid];
        out[g * fo + tid] = acc > 0.0f ? acc : 0.0f;
    }
}

// fallback FC2+FC3+log_softmax
__global__ __launch_bounds__(256) void k_fc23(const float* __restrict__ t1,
                                              const float* __restrict__ fw2,
                                              const float* __restrict__ fb2,
                                              const float* __restrict__ fw3,
                                              const float* __restrict__ fb3,
                                              float* __restrict__ out) {
    __shared__ float row[256];
    __shared__ float t2s[256];
    __shared__ float red[256];
    __shared__ float logits[100];
    const int g = blockIdx.x, tid = threadIdx.x;
    row[tid] = t1[g * 256 + tid];
    __syncthreads();
    float acc = fb2[tid];
    for (int k = 0; k < 256; ++k) acc += row[k] * fw2[k * 256 + tid];
    t2s[tid] = acc > 0.0f ? acc : 0.0f;
    __syncthreads();
    float v = -INFINITY;
    if (tid < 100) {
        float a3 = fb3[tid];
        for (int k = 0; k < 256; ++k) a3 += t2s[k] * fw3[k * 100 + tid];
        logits[tid] = a3;
        v = a3;
    }
    red[tid] = v;
    __syncthreads();
    for (int s = 128; s > 0; s >>= 1) {
        if (tid < s) red[tid] = fmaxf(red[tid], red[tid + s]);
        __syncthreads();
    }
    float mx = red[0];
    __syncthreads();
    red[tid] = (tid < 100) ? expf(logits[tid] - mx) : 0.0f;
    __syncthreads();
    for (int s = 128; s > 0; s >>= 1) {
        if (tid < s) red[tid] += red[tid + s];
        __syncthreads();
    }
    float lse = logf(red[0]);
    if (tid < 100) out[g * 100 + tid] = logits[tid] - mx - lse;
}

// ---------------- launch ----------------
extern "C" void kernel_launch(void* const* d_in, const int* in_sizes, int n_in,
                              void* d_out, int out_size, void* d_ws, size_t ws_size,
                              hipStream_t stream) {
    const float* pos = (const float*)d_in[0];
    const int* ei = (const int*)d_in[1];
    const float* p = (const float*)d_in[3];
    const float *W[5], *bb[5], *gg[5], *be[5];
    for (int i = 0; i < 5; ++i) {
        W[i]  = (const float*)d_in[4 + 4 * i];
        bb[i] = (const float*)d_in[5 + 4 * i];
        gg[i] = (const float*)d_in[6 + 4 * i];
        be[i] = (const float*)d_in[7 + 4 * i];
    }
    const float* fw1 = (const float*)d_in[24]; const float* fb1 = (const float*)d_in[25];
    const float* fw2 = (const float*)d_in[26]; const float* fb2 = (const float*)d_in[27];
    const float* fw3 = (const float*)d_in[28]; const float* fb3 = (const float*)d_in[29];
    float* out = (float*)d_out;

    const int fins[5]  = {3, 64, 128, 128, 256};
    const int kpads[5] = {32, 64, 128, 128, 256};
    const int fouts[5] = {64, 128, 128, 256, 512};

    size_t off = 0;
    char* base = (char*)d_ws;
    auto alloc = [&](size_t bytes) { char* q = base + off; off += (bytes + 255) & ~(size_t)255; return q; };

    float* Y      = (float*)alloc((size_t)NN * 512 * 4);
    float* Hf     = (float*)alloc((size_t)NN * 512 * 4);   // f32 fallback H; bf16 Hb aliases
    int*   remap  = (int*)alloc((size_t)NTOT * 4);
    int*   deg    = (int*)alloc(NN * 4);
    int*   cursor = (int*)alloc(NN * 4);
    int*   rowptr = (int*)alloc((NN + 1) * 4);
    int*   ecol   = (int*)alloc((size_t)NE * 4);
    float* ew     = (float*)alloc((size_t)NE * 4);
    float* gstat  = (float*)alloc(5 * 1024 * 4);           // per layer: 512 sum + 512 sumsq
    float* pooled = (float*)alloc(8 * 512 * 4);
    float* t1     = (float*)alloc(8 * 256 * 4);
    unsigned short* Ab0 = (unsigned short*)alloc((size_t)NN * 32 * 2);
    float* part   = (float*)alloc((size_t)256 * 512 * 4);
    unsigned short* WT[5];
    for (int l = 0; l < 5; ++l) WT[l] = (unsigned short*)alloc((size_t)fouts[l] * kpads[l] * 2);
    unsigned short* Hb = (unsigned short*)Hf;
    const bool mfma = (ws_size >= off);

    k_topk2<<<BGR, 1024, 0, stream>>>(pos, p, remap, Y, Ab0, deg, cursor);
    k_deg<<<NE / 256, 256, 0, stream>>>(ei, remap, deg, gstat);
    k_scan<<<1, 1024, 0, stream>>>(deg, rowptr);
    k_place2<<<NE / 256, 256, 0, stream>>>(ei, remap, deg, rowptr, cursor, ecol, ew);

    if (mfma) {
        k_wt_all<<<(190464 + 255) / 256, 256, 0, stream>>>(W[0], W[1], W[2], W[3], W[4],
                                                           WT[0], WT[1], WT[2], WT[3], WT[4]);
        for (int l = 0; l < 5; ++l) {
            int fo = fouts[l];
            if (l == 0)
                k_mm2<<<NN / 64, 256, 0, stream>>>(Ab0, nullptr, nullptr, nullptr, nullptr,
                                                   WT[l], Hb, kpads[l], fo);
            else
                k_mm2<<<NN / 64, 256, 0, stream>>>(nullptr, Y, gstat + (l - 1) * 1024,
                                                   gg[l - 1], be[l - 1],
                                                   WT[l], Hb, kpads[l], fo);
            k_gfuse<<<BN1_CHUNKS * (fo >> 6), 256, 0, stream>>>(Hb, nullptr, rowptr, ecol, ew,
                                                                deg, bb[l], Y,
                                                                gstat + l * 1024, fo);
        }
        k_pool_af<<<256, 256, 0, stream>>>(Y, gstat + 4 * 1024, gg[4], be[4], part);
        k_fc123<<<8, 256, 0, stream>>>(part, fw1, fb1, fw2, fb2, fw3, fb3, out, 32);
    } else {
        for (int l = 0; l < 5; ++l) {
            int fi = fins[l], fo = fouts[l];
            dim3 mg(NN / BM, fo / BNT);
            k_mm<<<mg, 256, 0, stream>>>(Y, W[l], Hf, fi, fo);
            k_gfuse<<<BN1_CHUNKS * (fo >> 6), 256, 0, stream>>>(nullptr, Hf, rowptr, ecol, ew,
                                                                deg, bb[l], Y,
                                                                gstat + l * 1024, fo);
            k_bnapply<<<(NN * fo) / 1024, 256, 0, stream>>>(Y, gstat + l * 1024,
                                                            gg[l], be[l], fo);
        }
        k_pool<<<64, 256, 0, stream>>>(Y, pooled);
        k_fc<<<8, 256, 0, stream>>>(pooled, fw1, fb1, t1, 512, 256);
        k_fc23<<<8, 256, 0, stream>>>(t1, fw2, fb2, fw3, fb3, out);
    }
}

// Round 12
// 279.691 us; speedup vs baseline: 1.1345x; 1.1345x over previous
//
#include <hip/hip_runtime.h>
#include <math.h>

#define NTOT 32768   // B*NP
#define NPG  4096    // nodes per graph
#define BGR  8       // graphs
#define KK   1024    // top-k
#define NN   8192    // B*K kept nodes
#define NE   262144  // edges

typedef __attribute__((ext_vector_type(8))) short bf16x8;
typedef __attribute__((ext_vector_type(4))) float f32x4;

static __device__ __forceinline__ unsigned short f2bf(float f) {
    unsigned u = __float_as_uint(f);
    return (unsigned short)((u + 0x7fffu + ((u >> 16) & 1u)) >> 16);
}
static __device__ __forceinline__ float bf2f(unsigned short b) {
    return __uint_as_float(((unsigned)b) << 16);
}

// ---------------- top-k per graph: radix select + ordered compaction ----------------
// Also initializes remap (all 4096 nodes of its graph) and zeroes deg/cursor slice.
__global__ __launch_bounds__(1024) void k_topk2(const float* __restrict__ pos,
                                                const float* __restrict__ p,
                                                int* __restrict__ remap,
                                                float* __restrict__ x0f,
                                                unsigned short* __restrict__ Ab0,
                                                int* __restrict__ deg,
                                                int* __restrict__ cursor) {
    __shared__ unsigned skey[NPG];
    __shared__ float sval[NPG];
    __shared__ int hist[256];
    __shared__ int Sarr[256];
    __shared__ int wsum[16];
    __shared__ int s_bin, s_above;

    const int g = blockIdx.x, tid = threadIdx.x;
    const int lane = tid & 63, wid = tid >> 6;
    deg[g * KK + tid] = 0;
    cursor[g * KK + tid] = 0;
    const float p0 = p[0], p1 = p[1], p2 = p[2];
    const float invn = 1.0f / sqrtf(p0 * p0 + p1 * p1 + p2 * p2);

    for (int i = tid; i < NPG; i += 1024) {
        const float* pp = pos + (size_t)(g * NPG + i) * 3;
        float s = tanhf((pp[0] * p0 + pp[1] * p1 + pp[2] * p2) * invn);
        sval[i] = s;
        unsigned b = __float_as_uint(s);
        skey[i] = (b & 0x80000000u) ? ~b : (b | 0x80000000u);
    }
    __syncthreads();

    unsigned prefix = 0;
    int needed = KK;
    for (int r = 0; r < 4; ++r) {
        const int sh = 24 - 8 * r;
        if (tid < 256) hist[tid] = 0;
        __syncthreads();
        for (int i = tid; i < NPG; i += 1024) {
            unsigned k = skey[i];
            bool act = (r == 0) || ((k >> (sh + 8)) == prefix);
            if (act) atomicAdd(&hist[(k >> sh) & 255u], 1);
        }
        __syncthreads();
        if (wid == 0) {
            int h0 = hist[4 * lane + 0], h1 = hist[4 * lane + 1];
            int h2 = hist[4 * lane + 2], h3 = hist[4 * lane + 3];
            int l3 = h3, l2 = h2 + l3, l1 = h1 + l2, l0 = h0 + l1;
            int t = l0;
            for (int off = 1; off < 64; off <<= 1) {
                int n = __shfl_down(t, off, 64);
                if (lane + off < 64) t += n;
            }
            int hi = t - l0;
            Sarr[4 * lane + 0] = l0 + hi;
            Sarr[4 * lane + 1] = l1 + hi;
            Sarr[4 * lane + 2] = l2 + hi;
            Sarr[4 * lane + 3] = l3 + hi;
        }
        __syncthreads();
        if (tid < 256) {
            int Sb = Sarr[tid];
            int Sb1 = (tid < 255) ? Sarr[tid + 1] : 0;
            if (Sb >= needed && Sb1 < needed) { s_bin = tid; s_above = Sb1; }
        }
        __syncthreads();
        needed -= s_above;
        prefix = (prefix << 8) | (unsigned)s_bin;
        __syncthreads();
    }
    const unsigned Tkey = prefix;
    const int needTies = needed;

    int tiebase = 0, keepbase = 0;
    for (int c = 0; c < 4; ++c) {
        const int i = c * 1024 + tid;
        const unsigned k = skey[i];
        const int tie = (k == Tkey) ? 1 : 0;
        int v = tie;
        for (int off = 1; off < 64; off <<= 1) {
            int n = __shfl_up(v, off, 64);
            if (lane >= off) v += n;
        }
        if (lane == 63) wsum[wid] = v;
        __syncthreads();
        if (wid == 0) {
            int w = (lane < 16) ? wsum[lane] : 0;
            for (int off = 1; off < 16; off <<= 1) {
                int n = __shfl_up(w, off, 64);
                if (lane >= off) w += n;
            }
            if (lane < 16) wsum[lane] = w;
        }
        __syncthreads();
        const int trank = tiebase + v + (wid > 0 ? wsum[wid - 1] : 0) - tie;
        const int ttot = wsum[15];
        const int keep = (k > Tkey) || (tie && trank < needTies);
        __syncthreads();
        int u = keep;
        for (int off = 1; off < 64; off <<= 1) {
            int n = __shfl_up(u, off, 64);
            if (lane >= off) u += n;
        }
        if (lane == 63) wsum[wid] = u;
        __syncthreads();
        if (wid == 0) {
            int w = (lane < 16) ? wsum[lane] : 0;
            for (int off = 1; off < 16; off <<= 1) {
                int n = __shfl_up(w, off, 64);
                if (lane >= off) w += n;
            }
            if (lane < 16) wsum[lane] = w;
        }
        __syncthreads();
        const int kincl = u + (wid > 0 ? wsum[wid - 1] : 0);
        const int ktot = wsum[15];
        if (keep) {
            int nn = g * KK + keepbase + kincl - 1;
            remap[g * NPG + i] = nn;
            float val = sval[i];
            const float* pp = pos + (size_t)(g * NPG + i) * 3;
            float v0 = pp[0] * val, v1 = pp[1] * val, v2 = pp[2] * val;
            x0f[(size_t)nn * 3 + 0] = v0;
            x0f[(size_t)nn * 3 + 1] = v1;
            x0f[(size_t)nn * 3 + 2] = v2;
            unsigned short* rw = Ab0 + (size_t)nn * 32;
            ushort4 a = make_ushort4(f2bf(v0), f2bf(v1), f2bf(v2), 0);
            ushort4 z = make_ushort4(0, 0, 0, 0);
            *(ushort4*)(rw) = a;
#pragma unroll
            for (int t = 1; t < 8; ++t) *(ushort4*)(rw + 4 * t) = z;
        } else {
            remap[g * NPG + i] = -1;
        }
        tiebase += ttot;
        keepbase += ktot;
        __syncthreads();
    }
}

// ---------------- pass 1: in-degree (+ zero the 5-layer BN stat accumulators) ----------------
__global__ void k_deg(const int* __restrict__ ei, const int* __restrict__ remap,
                      int* __restrict__ deg, float* __restrict__ gstatAll) {
    int e = blockIdx.x * blockDim.x + threadIdx.x;
    if (e < 5 * 1024) gstatAll[e] = 0.0f;
    if (e >= NE) return;
    int s = remap[ei[e]];
    int d = remap[ei[NE + e]];
    if (s >= 0 && d >= 0) atomicAdd(&deg[d], 1);
}

// ---------------- exclusive scan of deg -> rowptr ----------------
__global__ __launch_bounds__(1024) void k_scan(const int* __restrict__ deg,
                                               int* __restrict__ rowptr) {
    __shared__ int part[1024];
    const int tid = threadIdx.x;
    const int base = tid * 8;
    int loc[8];
    int s = 0;
#pragma unroll
    for (int i = 0; i < 8; ++i) { loc[i] = s; s += deg[base + i]; }
    part[tid] = s;
    __syncthreads();
    for (int off = 1; off < 1024; off <<= 1) {
        int v = (tid >= off) ? part[tid - off] : 0;
        __syncthreads();
        part[tid] += v;
        __syncthreads();
    }
    int pre = (tid > 0) ? part[tid - 1] : 0;
#pragma unroll
    for (int i = 0; i < 8; ++i) rowptr[base + i] = pre + loc[i];
    if (tid == 1023) rowptr[NN] = pre + s;
}

// ---------------- pass 2: place edges into CSR (by dst) ----------------
__global__ void k_place2(const int* __restrict__ ei, const int* __restrict__ remap,
                         const int* __restrict__ deg, const int* __restrict__ rowptr,
                         int* __restrict__ cursor, int* __restrict__ col,
                         float* __restrict__ ew) {
    int e = blockIdx.x * blockDim.x + threadIdx.x;
    if (e >= NE) return;
    int s = remap[ei[e]];
    int d = remap[ei[NE + e]];
    if (s >= 0 && d >= 0) {
        int pos = rowptr[d] + atomicAdd(&cursor[d], 1);
        col[pos] = s;
        ew[pos] = rsqrtf((float)(deg[s] + 1)) * rsqrtf((float)(deg[d] + 1));
    }
}

// ---------------- all weights transpose + bf16 convert, one launch ----------------
__global__ void k_wt_all(const float* __restrict__ w0, const float* __restrict__ w1,
                         const float* __restrict__ w2, const float* __restrict__ w3,
                         const float* __restrict__ w4,
                         unsigned short* __restrict__ t0, unsigned short* __restrict__ t1,
                         unsigned short* __restrict__ t2, unsigned short* __restrict__ t3,
                         unsigned short* __restrict__ t4) {
    int i = blockIdx.x * blockDim.x + threadIdx.x;
    const float* W; unsigned short* T; int Kd, Nc, Kpad, base;
    if (i < 2048)        { W = w0; T = t0; Kd = 3;   Nc = 64;  Kpad = 32;  base = 0; }
    else if (i < 10240)  { W = w1; T = t1; Kd = 64;  Nc = 128; Kpad = 64;  base = 2048; }
    else if (i < 26624)  { W = w2; T = t2; Kd = 128; Nc = 128; Kpad = 128; base = 10240; }
    else if (i < 59392)  { W = w3; T = t3; Kd = 128; Nc = 256; Kpad = 128; base = 26624; }
    else if (i < 190464) { W = w4; T = t4; Kd = 256; Nc = 512; Kpad = 256; base = 59392; }
    else return;
    int j = i - base;
    int n = j / Kpad, k = j - n * Kpad;
    float v = (k < Kd) ? W[(size_t)k * Nc + n] : 0.0f;
    T[j] = f2bf(v);
}

// ---------------- MFMA bf16 GEMM: Hb = bf16(A @ W)  [round-10 shape, gstat BN] ----------------
// A source: bf16 Ab0 (l=0) or f32 Yin with fused BN(gstat)+relu+bf16 (l>=1).
// Grid (NN/64, Nc/64); 4 waves per block, wave = 32x32.
__global__ __launch_bounds__(256) void k_mm2(const unsigned short* __restrict__ Ab0,
                                             const float* __restrict__ Yin,
                                             const float* __restrict__ gstat,
                                             const float* __restrict__ gamma,
                                             const float* __restrict__ beta,
                                             const unsigned short* __restrict__ WT,
                                             unsigned short* __restrict__ Hb,
                                             int Kd, int Nc) {
    __shared__ float sc_s[256], sh_s[256];
    const int tid = threadIdx.x;
    if (Yin) {
        if (tid < Kd) {
            double mean = (double)gstat[tid] / 8192.0;
            double var = (double)gstat[512 + tid] / 8192.0 - mean * mean;
            float sc = (float)((double)gamma[tid] / sqrt(var + 1e-5));
            sc_s[tid] = sc;
            sh_s[tid] = beta[tid] - (float)mean * sc;
        }
        __syncthreads();
    }
    const int lane = tid & 63, wid = tid >> 6;
    const int bm = blockIdx.x * 64 + (wid >> 1) * 32;
    const int bn = blockIdx.y * 64 + (wid & 1) * 32;
    const int fr = lane & 15;
    const int ko = (lane >> 4) << 3;
    const int row0 = bm + fr;
    const unsigned short* B0 = WT + (size_t)(bn + fr) * Kd + ko;
    const size_t strA = (size_t)16 * Kd;
    f32x4 acc00 = {0,0,0,0}, acc01 = {0,0,0,0}, acc10 = {0,0,0,0}, acc11 = {0,0,0,0};
    for (int k0 = 0; k0 < Kd; k0 += 32) {
        bf16x8 a0, a1;
        if (Yin) {
            const int cc = ko + k0;
            const float4 sc0 = *(const float4*)&sc_s[cc];
            const float4 sc1 = *(const float4*)&sc_s[cc + 4];
            const float4 sh0 = *(const float4*)&sh_s[cc];
            const float4 sh1 = *(const float4*)&sh_s[cc + 4];
            const float* y0 = Yin + (size_t)row0 * Kd + cc;
            const float* y1 = y0 + strA;
#pragma unroll
            for (int h = 0; h < 2; ++h) {
                const float* yy = h ? y1 : y0;
                float4 u = *(const float4*)yy;
                float4 v = *(const float4*)(yy + 4);
                bf16x8 a;
                a[0] = (short)f2bf(fmaxf(u.x * sc0.x + sh0.x, 0.0f));
                a[1] = (short)f2bf(fmaxf(u.y * sc0.y + sh0.y, 0.0f));
                a[2] = (short)f2bf(fmaxf(u.z * sc0.z + sh0.z, 0.0f));
                a[3] = (short)f2bf(fmaxf(u.w * sc0.w + sh0.w, 0.0f));
                a[4] = (short)f2bf(fmaxf(v.x * sc1.x + sh1.x, 0.0f));
                a[5] = (short)f2bf(fmaxf(v.y * sc1.y + sh1.y, 0.0f));
                a[6] = (short)f2bf(fmaxf(v.z * sc1.z + sh1.z, 0.0f));
                a[7] = (short)f2bf(fmaxf(v.w * sc1.w + sh1.w, 0.0f));
                if (h) a1 = a; else a0 = a;
            }
        } else {
            const unsigned short* A0 = Ab0 + (size_t)row0 * Kd + ko + k0;
            a0 = *(const bf16x8*)A0;
            a1 = *(const bf16x8*)(A0 + strA);
        }
        bf16x8 b0 = *(const bf16x8*)(B0 + k0);
        bf16x8 b1 = *(const bf16x8*)(B0 + strA + k0);
        acc00 = __builtin_amdgcn_mfma_f32_16x16x32_bf16(b0, a0, acc00, 0, 0, 0);
        acc01 = __builtin_amdgcn_mfma_f32_16x16x32_bf16(b1, a0, acc01, 0, 0, 0);
        acc10 = __builtin_amdgcn_mfma_f32_16x16x32_bf16(b0, a1, acc10, 0, 0, 0);
        acc11 = __builtin_amdgcn_mfma_f32_16x16x32_bf16(b1, a1, acc11, 0, 0, 0);
    }
    const int r = lane & 15;
    const int c4 = (lane >> 4) << 2;
#pragma unroll
    for (int tm = 0; tm < 2; ++tm) {
        const int row = bm + tm * 16 + r;
        const size_t basep = (size_t)row * Nc;
        const f32x4 aL = tm ? acc10 : acc00;
        const f32x4 aR = tm ? acc11 : acc01;
#pragma unroll
        for (int tn = 0; tn < 2; ++tn) {
            const f32x4 a = tn ? aR : aL;
            const int c = bn + tn * 16 + c4;
            *(ushort4*)&Hb[basep + c] = make_ushort4(f2bf(a[0]), f2bf(a[1]),
                                                     f2bf(a[2]), f2bf(a[3]));
        }
    }
}

// ---------------- f32 fallback matmul ----------------
#define BM 64
#define BNT 64
#define BKT 16
__global__ __launch_bounds__(256) void k_mm(const float* __restrict__ A,
                                            const float* __restrict__ W,
                                            float* __restrict__ H, int Kd, int Nc) {
    __shared__ float As[BM][BKT + 1];
    __shared__ float Bs[BKT][BNT + 1];
    const int bm = blockIdx.x * BM;
    const int bn = blockIdx.y * BNT;
    const int tid = threadIdx.x;
    const int tx = tid & 15, ty = tid >> 4;
    float acc[4][4] = {};
    for (int k0 = 0; k0 < Kd; k0 += BKT) {
        for (int t = 0; t < 4; ++t) {
            int i = tid + t * 256;
            int m = i >> 4, k = i & 15;
            As[m][k] = (k0 + k < Kd) ? A[(size_t)(bm + m) * Kd + k0 + k] : 0.0f;
        }
        for (int t = 0; t < 4; ++t) {
            int i = tid + t * 256;
            int k = i >> 6, n = i & 63;
            Bs[k][n] = (k0 + k < Kd) ? W[(size_t)(k0 + k) * Nc + bn + n] : 0.0f;
        }
        __syncthreads();
        for (int k = 0; k < BKT; ++k) {
            float a[4], b[4];
#pragma unroll
            for (int i = 0; i < 4; ++i) a[i] = As[ty * 4 + i][k];
#pragma unroll
            for (int j = 0; j < 4; ++j) b[j] = Bs[k][tx * 4 + j];
#pragma unroll
            for (int i = 0; i < 4; ++i)
#pragma unroll
                for (int j = 0; j < 4; ++j) acc[i][j] += a[i] * b[j];
        }
        __syncthreads();
    }
#pragma unroll
    for (int i = 0; i < 4; ++i)
        *(float4*)&H[(size_t)(bm + ty * 4 + i) * Nc + bn + tx * 4] =
            make_float4(acc[i][0], acc[i][1], acc[i][2], acc[i][3]);
}

// ---------------- fused: Y = H*inv + bias + CSR-gather; BN stats via atomics ----------------
#define BN1_ROWS 32
#define BN1_CHUNKS (NN / BN1_ROWS)   // 256
__global__ __launch_bounds__(256) void k_gfuse(const unsigned short* __restrict__ Hb,
                                               const float* __restrict__ Hf,
                                               const int* __restrict__ rowptr,
                                               const int* __restrict__ col,
                                               const float* __restrict__ ew,
                                               const int* __restrict__ deg,
                                               const float* __restrict__ bias,
                                               float* __restrict__ Y,
                                               float* __restrict__ gstat, int Nc) {
    __shared__ float4 ls[256], lq[256];
    const int CB = Nc >> 6;
    const int chunk = blockIdx.x / CB;
    const int cb = blockIdx.x - chunk * CB;
    const int tid = threadIdx.x;
    const int q = tid & 15;
    const int rg = tid >> 4;
    const int c = cb * 64 + (q << 2);
    const float4 b4 = *(const float4*)&bias[c];
    float4 s4 = make_float4(0, 0, 0, 0), q4 = make_float4(0, 0, 0, 0);
#pragma unroll
    for (int rr = 0; rr < 2; ++rr) {
        const int n = chunk * BN1_ROWS + rg * 2 + rr;
        const int j0 = rowptr[n], j1 = rowptr[n + 1];
        const float inv = 1.0f / (float)(deg[n] + 1);
        float4 acc;
        if (Hb) {
            ushort4 hv = *(const ushort4*)&Hb[(size_t)n * Nc + c];
            acc = make_float4(bf2f(hv.x), bf2f(hv.y), bf2f(hv.z), bf2f(hv.w));
        } else {
            acc = *(const float4*)&Hf[(size_t)n * Nc + c];
        }
        acc.x = acc.x * inv + b4.x;
        acc.y = acc.y * inv + b4.y;
        acc.z = acc.z * inv + b4.z;
        acc.w = acc.w * inv + b4.w;
        if (Hb) {
            for (int j = j0; j < j1; ++j) {
                const float w = ew[j];
                ushort4 hv = *(const ushort4*)&Hb[(size_t)col[j] * Nc + c];
                acc.x += bf2f(hv.x) * w; acc.y += bf2f(hv.y) * w;
                acc.z += bf2f(hv.z) * w; acc.w += bf2f(hv.w) * w;
            }
        } else {
            for (int j = j0; j < j1; ++j) {
                const float w = ew[j];
                const float4 hv = *(const float4*)&Hf[(size_t)col[j] * Nc + c];
                acc.x += hv.x * w; acc.y += hv.y * w; acc.z += hv.z * w; acc.w += hv.w * w;
            }
        }
        *(float4*)&Y[(size_t)n * Nc + c] = acc;
        s4.x += acc.x; s4.y += acc.y; s4.z += acc.z; s4.w += acc.w;
        q4.x += acc.x * acc.x; q4.y += acc.y * acc.y;
        q4.z += acc.z * acc.z; q4.w += acc.w * acc.w;
    }
    ls[tid] = s4; lq[tid] = q4;
    __syncthreads();
    for (int st = 128; st >= 16; st >>= 1) {
        if (tid < st) {
            float4 a = ls[tid], b = ls[tid + st];
            ls[tid] = make_float4(a.x + b.x, a.y + b.y, a.z + b.z, a.w + b.w);
            float4 e = lq[tid], f = lq[tid + st];
            lq[tid] = make_float4(e.x + f.x, e.y + f.y, e.z + f.z, e.w + f.w);
        }
        __syncthreads();
    }
    if (tid < 16) {
        float4 a = ls[tid], b = lq[tid];
        atomicAdd(&gstat[c + 0], a.x); atomicAdd(&gstat[c + 1], a.y);
        atomicAdd(&gstat[c + 2], a.z); atomicAdd(&gstat[c + 3], a.w);
        atomicAdd(&gstat[512 + c + 0], b.x); atomicAdd(&gstat[512 + c + 1], b.y);
        atomicAdd(&gstat[512 + c + 2], b.z); atomicAdd(&gstat[512 + c + 3], b.w);
    }
}

// f32 fallback bn-apply (scale/shift from gstat inline)
__global__ void k_bnapply(float* x, const float* __restrict__ gstat,
                          const float* __restrict__ gamma, const float* __restrict__ beta,
                          int Nc) {
    int i = blockIdx.x * blockDim.x + threadIdx.x;
    int c0 = (i & ((Nc >> 2) - 1)) << 2;
    float4 v = ((const float4*)x)[i];
    float r[4] = {v.x, v.y, v.z, v.w};
#pragma unroll
    for (int k = 0; k < 4; ++k) {
        int c = c0 + k;
        double mean = (double)gstat[c] / 8192.0;
        double var = (double)gstat[512 + c] / 8192.0 - mean * mean;
        float sc = (float)((double)gamma[c] / sqrt(var + 1e-5));
        float sh = beta[c] - (float)mean * sc;
        r[k] = fmaxf(r[k] * sc + sh, 0.0f);
    }
    ((float4*)x)[i] = make_float4(r[0], r[1], r[2], r[3]);
}

// ---------------- pool stage A with fused BN+relu (reads Y f32, stats from gstat) ----------------
#define PR 32
__global__ __launch_bounds__(256) void k_pool_af(const float* __restrict__ Y,
                                                 const float* __restrict__ gstat,
                                                 const float* __restrict__ gamma,
                                                 const float* __restrict__ beta,
                                                 float* __restrict__ part) {
    __shared__ float4 red[128];
    const int g = blockIdx.x >> 5;
    const int rs = blockIdx.x & 31;
    const int half = threadIdx.x >> 7;
    const int q = threadIdx.x & 127;
    const int c = 4 * q;
    float4 sc, sh;
    {
        double m0 = (double)gstat[c + 0] / 8192.0;
        double v0 = (double)gstat[512 + c + 0] / 8192.0 - m0 * m0;
        sc.x = (float)((double)gamma[c + 0] / sqrt(v0 + 1e-5));
        sh.x = beta[c + 0] - (float)m0 * sc.x;
        double m1 = (double)gstat[c + 1] / 8192.0;
        double v1 = (double)gstat[512 + c + 1] / 8192.0 - m1 * m1;
        sc.y = (float)((double)gamma[c + 1] / sqrt(v1 + 1e-5));
        sh.y = beta[c + 1] - (float)m1 * sc.y;
        double m2 = (double)gstat[c + 2] / 8192.0;
        double v2 = (double)gstat[512 + c + 2] / 8192.0 - m2 * m2;
        sc.z = (float)((double)gamma[c + 2] / sqrt(v2 + 1e-5));
        sh.z = beta[c + 2] - (float)m2 * sc.z;
        double m3 = (double)gstat[c + 3] / 8192.0;
        double v3 = (double)gstat[512 + c + 3] / 8192.0 - m3 * m3;
        sc.w = (float)((double)gamma[c + 3] / sqrt(v3 + 1e-5));
        sh.w = beta[c + 3] - (float)m3 * sc.w;
    }
    const float* xp = Y + (size_t)(g * KK + rs * PR + half * 16) * 512 + c;
    float4 s = make_float4(0, 0, 0, 0);
#pragma unroll
    for (int rr = 0; rr < 16; ++rr) {
        float4 v = *(const float4*)(xp + (size_t)rr * 512);
        s.x += fmaxf(v.x * sc.x + sh.x, 0.0f);
        s.y += fmaxf(v.y * sc.y + sh.y, 0.0f);
        s.z += fmaxf(v.z * sc.z + sh.z, 0.0f);
        s.w += fmaxf(v.w * sc.w + sh.w, 0.0f);
    }
    if (half == 1) red[q] = s;
    __syncthreads();
    if (half == 0) {
        float4 t = red[q];
        s.x += t.x; s.y += t.y; s.z += t.z; s.w += t.w;
        *(float4*)&part[(size_t)blockIdx.x * 512 + c] = s;
    }
}

// f32 fallback pool
__global__ __launch_bounds__(256) void k_pool(const float* __restrict__ x, float* pooled) {
    __shared__ float red[4][64];
    int g = blockIdx.x >> 3;
    int c0 = (blockIdx.x & 7) * 64;
    int c = threadIdx.x & 63;
    int rp = threadIdx.x >> 6;
    float s = 0;
    for (int r = rp; r < KK; r += 4)
        s += x[(size_t)(g * KK + r) * 512 + c0 + c];
    red[rp][c] = s;
    __syncthreads();
    if (rp == 0)
        pooled[g * 512 + c0 + c] = red[0][c] + red[1][c] + red[2][c] + red[3][c];
}

// ---------------- FC1 k-split: grid (8 graphs, 16 slices of 32 k) ----------------
__global__ __launch_bounds__(256) void k_fc1s(const float* __restrict__ part,
                                              const float* __restrict__ fw1,
                                              float* __restrict__ part2) {
    __shared__ float pooled_s[32];
    __shared__ float red[256];
    const int g = blockIdx.x, s = blockIdx.y, tid = threadIdx.x;
    const int j = tid & 31;   // k within slice
    const int i = tid >> 5;   // 0..7
    float p = 0;
    for (int a = i; a < 32; a += 8)
        p += part[(size_t)(g * 32 + a) * 512 + 32 * s + j];
    red[tid] = p;
    __syncthreads();
    if (tid < 32) {
        float t = red[tid];
        for (int i2 = 1; i2 < 8; ++i2) t += red[i2 * 32 + tid];
        pooled_s[tid] = t;
    }
    __syncthreads();
    float acc = 0;
    const float* wp = fw1 + (size_t)(32 * s) * 256 + tid;
#pragma unroll
    for (int k = 0; k < 32; ++k) acc += pooled_s[k] * wp[k * 256];
    part2[(size_t)(g * 16 + s) * 256 + tid] = acc;
}

// ---------------- FC2 k-split: grid (8 graphs, 8 slices of 32 k) ----------------
__global__ __launch_bounds__(256) void k_fc2s(const float* __restrict__ part2,
                                              const float* __restrict__ fb1,
                                              const float* __restrict__ fw2,
                                              float* __restrict__ part3) {
    __shared__ float t1s[256];
    const int g = blockIdx.x, s = blockIdx.y, tid = threadIdx.x;
    float a1 = fb1[tid];
    for (int i = 0; i < 16; ++i) a1 += part2[(size_t)(g * 16 + i) * 256 + tid];
    t1s[tid] = fmaxf(a1, 0.0f);
    __syncthreads();
    float acc = 0;
    const float* wp = fw2 + (size_t)(32 * s) * 256 + tid;
#pragma unroll
    for (int k = 0; k < 32; ++k) acc += t1s[32 * s + k] * wp[k * 256];
    part3[(size_t)(g * 8 + s) * 256 + tid] = acc;
}

// ---------------- FC3 + log_softmax: 8 blocks ----------------
__global__ __launch_bounds__(256) void k_fc3f(const float* __restrict__ part3,
                                              const float* __restrict__ fb2,
                                              const float* __restrict__ fw3,
                                              const float* __restrict__ fb3,
                                              float* __restrict__ out) {
    __shared__ float t2s[256];
    __shared__ float red[256];
    __shared__ float logits[100];
    const int g = blockIdx.x, tid = threadIdx.x;
    float a2 = fb2[tid];
    for (int i = 0; i < 8; ++i) a2 += part3[(size_t)(g * 8 + i) * 256 + tid];
    t2s[tid] = fmaxf(a2, 0.0f);
    __syncthreads();
    float v = -INFINITY;
    if (tid < 100) {
        float a3 = fb3[tid];
        for (int k = 0; k < 256; ++k) a3 += t2s[k] * fw3[k * 100 + tid];
        logits[tid] = a3;
        v = a3;
    }
    red[tid] = v;
    __syncthreads();
    for (int s = 128; s > 0; s >>= 1) {
        if (tid < s) red[tid] = fmaxf(red[tid], red[tid + s]);
        __syncthreads();
    }
    float mx = red[0];
    __syncthreads();
    red[tid] = (tid < 100) ? expf(logits[tid] - mx) : 0.0f;
    __syncthreads();
    for (int s = 128; s > 0; s >>= 1) {
        if (tid < s) red[tid] += red[tid + s];
        __syncthreads();
    }
    float lse = logf(red[0]);
    if (tid < 100) out[g * 100 + tid] = logits[tid] - mx - lse;
}

// plain FC + relu (fallback path)
__global__ void k_fc(const float* __restrict__ in, const float* __restrict__ W,
                     const float* __restrict__ bias, float* out, int fi, int fo) {
    __shared__ float row[512];
    int g = blockIdx.x, tid = threadIdx.x;
    for (int k = tid; k < fi; k += blockDim.x) row[k] = in[g * fi + k];
    __syncthreads();
    if (tid < fo) {
        float acc = bias[tid];
        for (int k = 0; k < fi; ++k) acc += row[k] * W[k * fo + tid];
        out[g * fo + tid] = acc > 0.0f ? acc : 0.0f;
    }
}

// fallback FC2+FC3+log_softmax
__global__ __launch_bounds__(256) void k_fc23(const float* __restrict__ t1,
                                              const float* __restrict__ fw2,
                                              const float* __restrict__ fb2,
                                              const float* __restrict__ fw3,
                                              const float* __restrict__ fb3,
                                              float* __restrict__ out) {
    __shared__ float row[256];
    __shared__ float t2s[256];
    __shared__ float red[256];
    __shared__ float logits[100];
    const int g = blockIdx.x, tid = threadIdx.x;
    row[tid] = t1[g * 256 + tid];
    __syncthreads();
    float acc = fb2[tid];
    for (int k = 0; k < 256; ++k) acc += row[k] * fw2[k * 256 + tid];
    t2s[tid] = acc > 0.0f ? acc : 0.0f;
    __syncthreads();
    float v = -INFINITY;
    if (tid < 100) {
        float a3 = fb3[tid];
        for (int k = 0; k < 256; ++k) a3 += t2s[k] * fw3[k * 100 + tid];
        logits[tid] = a3;
        v = a3;
    }
    red[tid] = v;
    __syncthreads();
    for (int s = 128; s > 0; s >>= 1) {
        if (tid < s) red[tid] = fmaxf(red[tid], red[tid + s]);
        __syncthreads();
    }
    float mx = red[0];
    __syncthreads();
    red[tid] = (tid < 100) ? expf(logits[tid] - mx) : 0.0f;
    __syncthreads();
    for (int s = 128; s > 0; s >>= 1) {
        if (tid < s) red[tid] += red[tid + s];
        __syncthreads();
    }
    float lse = logf(red[0]);
    if (tid < 100) out[g * 100 + tid] = logits[tid] - mx - lse;
}

// ---------------- launch ----------------
extern "C" void kernel_launch(void* const* d_in, const int* in_sizes, int n_in,
                              void* d_out, int out_size, void* d_ws, size_t ws_size,
                              hipStream_t stream) {
    const float* pos = (const float*)d_in[0];
    const int* ei = (const int*)d_in[1];
    const float* p = (const float*)d_in[3];
    const float *W[5], *bb[5], *gg[5], *be[5];
    for (int i = 0; i < 5; ++i) {
        W[i]  = (const float*)d_in[4 + 4 * i];
        bb[i] = (const float*)d_in[5 + 4 * i];
        gg[i] = (const float*)d_in[6 + 4 * i];
        be[i] = (const float*)d_in[7 + 4 * i];
    }
    const float* fw1 = (const float*)d_in[24]; const float* fb1 = (const float*)d_in[25];
    const float* fw2 = (const float*)d_in[26]; const float* fb2 = (const float*)d_in[27];
    const float* fw3 = (const float*)d_in[28]; const float* fb3 = (const float*)d_in[29];
    float* out = (float*)d_out;

    const int fins[5]  = {3, 64, 128, 128, 256};
    const int kpads[5] = {32, 64, 128, 128, 256};
    const int fouts[5] = {64, 128, 128, 256, 512};

    size_t off = 0;
    char* base = (char*)d_ws;
    auto alloc = [&](size_t bytes) { char* q = base + off; off += (bytes + 255) & ~(size_t)255; return q; };

    float* Y      = (float*)alloc((size_t)NN * 512 * 4);
    float* Hf     = (float*)alloc((size_t)NN * 512 * 4);   // f32 fallback H; bf16 Hb aliases
    int*   remap  = (int*)alloc((size_t)NTOT * 4);
    int*   deg    = (int*)alloc(NN * 4);
    int*   cursor = (int*)alloc(NN * 4);
    int*   rowptr = (int*)alloc((NN + 1) * 4);
    int*   ecol   = (int*)alloc((size_t)NE * 4);
    float* ew     = (float*)alloc((size_t)NE * 4);
    float* gstat  = (float*)alloc(5 * 1024 * 4);           // per layer: 512 sum + 512 sumsq
    float* pooled = (float*)alloc(8 * 512 * 4);
    float* t1     = (float*)alloc(8 * 256 * 4);
    unsigned short* Ab0 = (unsigned short*)alloc((size_t)NN * 32 * 2);
    float* part   = (float*)alloc((size_t)256 * 512 * 4);
    float* part2  = (float*)alloc((size_t)8 * 16 * 256 * 4);
    float* part3  = (float*)alloc((size_t)8 * 8 * 256 * 4);
    unsigned short* WT[5];
    for (int l = 0; l < 5; ++l) WT[l] = (unsigned short*)alloc((size_t)fouts[l] * kpads[l] * 2);
    unsigned short* Hb = (unsigned short*)Hf;
    const bool mfma = (ws_size >= off);

    k_topk2<<<BGR, 1024, 0, stream>>>(pos, p, remap, Y, Ab0, deg, cursor);
    k_deg<<<NE / 256, 256, 0, stream>>>(ei, remap, deg, gstat);
    k_scan<<<1, 1024, 0, stream>>>(deg, rowptr);
    k_place2<<<NE / 256, 256, 0, stream>>>(ei, remap, deg, rowptr, cursor, ecol, ew);

    if (mfma) {
        k_wt_all<<<(190464 + 255) / 256, 256, 0, stream>>>(W[0], W[1], W[2], W[3], W[4],
                                                           WT[0], WT[1], WT[2], WT[3], WT[4]);
        for (int l = 0; l < 5; ++l) {
            int fo = fouts[l];
            dim3 mg(NN / 64, fo / 64);
            if (l == 0)
                k_mm2<<<mg, 256, 0, stream>>>(Ab0, nullptr, nullptr, nullptr, nullptr,
                                              WT[l], Hb, kpads[l], fo);
            else
                k_mm2<<<mg, 256, 0, stream>>>(nullptr, Y, gstat + (l - 1) * 1024,
                                              gg[l - 1], be[l - 1],
                                              WT[l], Hb, kpads[l], fo);
            k_gfuse<<<BN1_CHUNKS * (fo >> 6), 256, 0, stream>>>(Hb, nullptr, rowptr, ecol, ew,
                                                                deg, bb[l], Y,
                                                                gstat + l * 1024, fo);
        }
        k_pool_af<<<256, 256, 0, stream>>>(Y, gstat + 4 * 1024, gg[4], be[4], part);
        k_fc1s<<<dim3(8, 16), 256, 0, stream>>>(part, fw1, part2);
        k_fc2s<<<dim3(8, 8), 256, 0, stream>>>(part2, fb1, fw2, part3);
        k_fc3f<<<8, 256, 0, stream>>>(part3, fb2, fw3, fb3, out);
    } else {
        for (int l = 0; l < 5; ++l) {
            int fi = fins[l], fo = fouts[l];
            dim3 mg(NN / BM, fo / BNT);
            k_mm<<<mg, 256, 0, stream>>>(Y, W[l], Hf, fi, fo);
            k_gfuse<<<BN1_CHUNKS * (fo >> 6), 256, 0, stream>>>(nullptr, Hf, rowptr, ecol, ew,
                                                                deg, bb[l], Y,
                                                                gstat + l * 1024, fo);
            k_bnapply<<<(NN * fo) / 1024, 256, 0, stream>>>(Y, gstat + l * 1024,
                                                            gg[l], be[l], fo);
        }
        k_pool<<<64, 256, 0, stream>>>(Y, pooled);
        k_fc<<<8, 256, 0, stream>>>(pooled, fw1, fb1, t1, 512, 256);
        k_fc23<<<8, 256, 0, stream>>>(t1, fw2, fb2, fw3, fb3, out);
    }
}

// Round 13
// 184.102 us; speedup vs baseline: 1.7235x; 1.5192x over previous
//
#include <hip/hip_runtime.h>
#include <math.h>

#define NTOT 32768   // B*NP
#define NPG  4096    // nodes per graph
#define BGR  8       // graphs
#define KK   1024    // top-k
#define NN   8192    // B*K kept nodes
#define NE   262144  // edges

typedef __attribute__((ext_vector_type(8))) short bf16x8;
typedef __attribute__((ext_vector_type(4))) float f32x4;

static __device__ __forceinline__ unsigned short f2bf(float f) {
    unsigned u = __float_as_uint(f);
    return (unsigned short)((u + 0x7fffu + ((u >> 16) & 1u)) >> 16);
}
static __device__ __forceinline__ float bf2f(unsigned short b) {
    return __uint_as_float(((unsigned)b) << 16);
}

// ---------------- top-k per graph: radix select + ordered compaction ----------------
// Also initializes remap (its graph's 4096 nodes) and zeroes deg/cursor slice.
__global__ __launch_bounds__(1024) void k_topk2(const float* __restrict__ pos,
                                                const float* __restrict__ p,
                                                int* __restrict__ remap,
                                                float* __restrict__ x0f,
                                                unsigned short* __restrict__ Ab0,
                                                int* __restrict__ deg,
                                                int* __restrict__ cursor) {
    __shared__ unsigned skey[NPG];
    __shared__ float sval[NPG];
    __shared__ int hist[256];
    __shared__ int Sarr[256];
    __shared__ int wsum[16];
    __shared__ int s_bin, s_above;

    const int g = blockIdx.x, tid = threadIdx.x;
    const int lane = tid & 63, wid = tid >> 6;
    deg[g * KK + tid] = 0;
    cursor[g * KK + tid] = 0;
    const float p0 = p[0], p1 = p[1], p2 = p[2];
    const float invn = 1.0f / sqrtf(p0 * p0 + p1 * p1 + p2 * p2);

    for (int i = tid; i < NPG; i += 1024) {
        const float* pp = pos + (size_t)(g * NPG + i) * 3;
        float s = tanhf((pp[0] * p0 + pp[1] * p1 + pp[2] * p2) * invn);
        sval[i] = s;
        unsigned b = __float_as_uint(s);
        skey[i] = (b & 0x80000000u) ? ~b : (b | 0x80000000u);
    }
    __syncthreads();

    unsigned prefix = 0;
    int needed = KK;
    for (int r = 0; r < 4; ++r) {
        const int sh = 24 - 8 * r;
        if (tid < 256) hist[tid] = 0;
        __syncthreads();
        for (int i = tid; i < NPG; i += 1024) {
            unsigned k = skey[i];
            bool act = (r == 0) || ((k >> (sh + 8)) == prefix);
            if (act) atomicAdd(&hist[(k >> sh) & 255u], 1);
        }
        __syncthreads();
        if (wid == 0) {
            int h0 = hist[4 * lane + 0], h1 = hist[4 * lane + 1];
            int h2 = hist[4 * lane + 2], h3 = hist[4 * lane + 3];
            int l3 = h3, l2 = h2 + l3, l1 = h1 + l2, l0 = h0 + l1;
            int t = l0;
            for (int off = 1; off < 64; off <<= 1) {
                int n = __shfl_down(t, off, 64);
                if (lane + off < 64) t += n;
            }
            int hi = t - l0;
            Sarr[4 * lane + 0] = l0 + hi;
            Sarr[4 * lane + 1] = l1 + hi;
            Sarr[4 * lane + 2] = l2 + hi;
            Sarr[4 * lane + 3] = l3 + hi;
        }
        __syncthreads();
        if (tid < 256) {
            int Sb = Sarr[tid];
            int Sb1 = (tid < 255) ? Sarr[tid + 1] : 0;
            if (Sb >= needed && Sb1 < needed) { s_bin = tid; s_above = Sb1; }
        }
        __syncthreads();
        needed -= s_above;
        prefix = (prefix << 8) | (unsigned)s_bin;
        __syncthreads();
    }
    const unsigned Tkey = prefix;
    const int needTies = needed;

    int tiebase = 0, keepbase = 0;
    for (int c = 0; c < 4; ++c) {
        const int i = c * 1024 + tid;
        const unsigned k = skey[i];
        const int tie = (k == Tkey) ? 1 : 0;
        int v = tie;
        for (int off = 1; off < 64; off <<= 1) {
            int n = __shfl_up(v, off, 64);
            if (lane >= off) v += n;
        }
        if (lane == 63) wsum[wid] = v;
        __syncthreads();
        if (wid == 0) {
            int w = (lane < 16) ? wsum[lane] : 0;
            for (int off = 1; off < 16; off <<= 1) {
                int n = __shfl_up(w, off, 64);
                if (lane >= off) w += n;
            }
            if (lane < 16) wsum[lane] = w;
        }
        __syncthreads();
        const int trank = tiebase + v + (wid > 0 ? wsum[wid - 1] : 0) - tie;
        const int ttot = wsum[15];
        const int keep = (k > Tkey) || (tie && trank < needTies);
        __syncthreads();
        int u = keep;
        for (int off = 1; off < 64; off <<= 1) {
            int n = __shfl_up(u, off, 64);
            if (lane >= off) u += n;
        }
        if (lane == 63) wsum[wid] = u;
        __syncthreads();
        if (wid == 0) {
            int w = (lane < 16) ? wsum[lane] : 0;
            for (int off = 1; off < 16; off <<= 1) {
                int n = __shfl_up(w, off, 64);
                if (lane >= off) w += n;
            }
            if (lane < 16) wsum[lane] = w;
        }
        __syncthreads();
        const int kincl = u + (wid > 0 ? wsum[wid - 1] : 0);
        const int ktot = wsum[15];
        if (keep) {
            int nn = g * KK + keepbase + kincl - 1;
            remap[g * NPG + i] = nn;
            float val = sval[i];
            const float* pp = pos + (size_t)(g * NPG + i) * 3;
            float v0 = pp[0] * val, v1 = pp[1] * val, v2 = pp[2] * val;
            x0f[(size_t)nn * 3 + 0] = v0;
            x0f[(size_t)nn * 3 + 1] = v1;
            x0f[(size_t)nn * 3 + 2] = v2;
            unsigned short* rw = Ab0 + (size_t)nn * 32;
            ushort4 a = make_ushort4(f2bf(v0), f2bf(v1), f2bf(v2), 0);
            ushort4 z = make_ushort4(0, 0, 0, 0);
            *(ushort4*)(rw) = a;
#pragma unroll
            for (int t = 1; t < 8; ++t) *(ushort4*)(rw + 4 * t) = z;
        } else {
            remap[g * NPG + i] = -1;
        }
        tiebase += ttot;
        keepbase += ktot;
        __syncthreads();
    }
}

// ---------------- pass 1: in-degree ----------------
__global__ void k_deg(const int* __restrict__ ei, const int* __restrict__ remap,
                      int* __restrict__ deg) {
    int e = blockIdx.x * blockDim.x + threadIdx.x;
    if (e >= NE) return;
    int s = remap[ei[e]];
    int d = remap[ei[NE + e]];
    if (s >= 0 && d >= 0) atomicAdd(&deg[d], 1);
}

// ---------------- exclusive scan of deg -> rowptr ----------------
__global__ __launch_bounds__(1024) void k_scan(const int* __restrict__ deg,
                                               int* __restrict__ rowptr) {
    __shared__ int part[1024];
    const int tid = threadIdx.x;
    const int base = tid * 8;
    int loc[8];
    int s = 0;
#pragma unroll
    for (int i = 0; i < 8; ++i) { loc[i] = s; s += deg[base + i]; }
    part[tid] = s;
    __syncthreads();
    for (int off = 1; off < 1024; off <<= 1) {
        int v = (tid >= off) ? part[tid - off] : 0;
        __syncthreads();
        part[tid] += v;
        __syncthreads();
    }
    int pre = (tid > 0) ? part[tid - 1] : 0;
#pragma unroll
    for (int i = 0; i < 8; ++i) rowptr[base + i] = pre + loc[i];
    if (tid == 1023) rowptr[NN] = pre + s;
}

// ---------------- pass 2: place edges into CSR (by dst) ----------------
__global__ void k_place2(const int* __restrict__ ei, const int* __restrict__ remap,
                         const int* __restrict__ deg, const int* __restrict__ rowptr,
                         int* __restrict__ cursor, int* __restrict__ col,
                         float* __restrict__ ew) {
    int e = blockIdx.x * blockDim.x + threadIdx.x;
    if (e >= NE) return;
    int s = remap[ei[e]];
    int d = remap[ei[NE + e]];
    if (s >= 0 && d >= 0) {
        int pos = rowptr[d] + atomicAdd(&cursor[d], 1);
        col[pos] = s;
        ew[pos] = rsqrtf((float)(deg[s] + 1)) * rsqrtf((float)(deg[d] + 1));
    }
}

// ---------------- all weights transpose + bf16 convert, one launch ----------------
__global__ void k_wt_all(const float* __restrict__ w0, const float* __restrict__ w1,
                         const float* __restrict__ w2, const float* __restrict__ w3,
                         const float* __restrict__ w4,
                         unsigned short* __restrict__ t0, unsigned short* __restrict__ t1,
                         unsigned short* __restrict__ t2, unsigned short* __restrict__ t3,
                         unsigned short* __restrict__ t4) {
    int i = blockIdx.x * blockDim.x + threadIdx.x;
    const float* W; unsigned short* T; int Kd, Nc, Kpad, base;
    if (i < 2048)        { W = w0; T = t0; Kd = 3;   Nc = 64;  Kpad = 32;  base = 0; }
    else if (i < 10240)  { W = w1; T = t1; Kd = 64;  Nc = 128; Kpad = 64;  base = 2048; }
    else if (i < 26624)  { W = w2; T = t2; Kd = 128; Nc = 128; Kpad = 128; base = 10240; }
    else if (i < 59392)  { W = w3; T = t3; Kd = 128; Nc = 256; Kpad = 128; base = 26624; }
    else if (i < 190464) { W = w4; T = t4; Kd = 256; Nc = 512; Kpad = 256; base = 59392; }
    else return;
    int j = i - base;
    int n = j / Kpad, k = j - n * Kpad;
    float v = (k < Kd) ? W[(size_t)k * Nc + n] : 0.0f;
    T[j] = f2bf(v);
}

// ---------------- MFMA bf16 GEMM: Hb = bf16(A @ W)  [218-µs-verified shape] ----------------
// A source: bf16 Ab0 (l=0), or f32 Yin with fused BN(scale/shift)+relu+bf16 (l>=1).
// Grid (NN/64, Nc/64); 4 waves per block, wave = 32x32.
__global__ __launch_bounds__(256) void k_mm2(const unsigned short* __restrict__ Ab,
                                             const float* __restrict__ Yin,
                                             const float* __restrict__ scale,
                                             const float* __restrict__ shift,
                                             const unsigned short* __restrict__ WT,
                                             unsigned short* __restrict__ Hb,
                                             int Kd, int Nc) {
    const int lane = threadIdx.x & 63, wid = threadIdx.x >> 6;
    const int bm = blockIdx.x * 64 + (wid >> 1) * 32;
    const int bn = blockIdx.y * 64 + (wid & 1) * 32;
    const int fr = lane & 15;
    const int ko = (lane >> 4) << 3;
    const int row0 = bm + fr;
    const unsigned short* B0 = WT + (size_t)(bn + fr) * Kd + ko;
    const size_t strA = (size_t)16 * Kd;
    f32x4 acc00 = {0,0,0,0}, acc01 = {0,0,0,0}, acc10 = {0,0,0,0}, acc11 = {0,0,0,0};
    for (int k0 = 0; k0 < Kd; k0 += 32) {
        bf16x8 a0, a1;
        if (Yin) {
            const int cc = ko + k0;
            const float4 sc0 = *(const float4*)&scale[cc];
            const float4 sc1 = *(const float4*)&scale[cc + 4];
            const float4 sh0 = *(const float4*)&shift[cc];
            const float4 sh1 = *(const float4*)&shift[cc + 4];
            const float* y0 = Yin + (size_t)row0 * Kd + cc;
            const float* y1 = y0 + strA;
#pragma unroll
            for (int h = 0; h < 2; ++h) {
                const float* yy = h ? y1 : y0;
                float4 u = *(const float4*)yy;
                float4 v = *(const float4*)(yy + 4);
                bf16x8 a;
                a[0] = (short)f2bf(fmaxf(u.x * sc0.x + sh0.x, 0.0f));
                a[1] = (short)f2bf(fmaxf(u.y * sc0.y + sh0.y, 0.0f));
                a[2] = (short)f2bf(fmaxf(u.z * sc0.z + sh0.z, 0.0f));
                a[3] = (short)f2bf(fmaxf(u.w * sc0.w + sh0.w, 0.0f));
                a[4] = (short)f2bf(fmaxf(v.x * sc1.x + sh1.x, 0.0f));
                a[5] = (short)f2bf(fmaxf(v.y * sc1.y + sh1.y, 0.0f));
                a[6] = (short)f2bf(fmaxf(v.z * sc1.z + sh1.z, 0.0f));
                a[7] = (short)f2bf(fmaxf(v.w * sc1.w + sh1.w, 0.0f));
                if (h) a1 = a; else a0 = a;
            }
        } else {
            const unsigned short* A0 = Ab + (size_t)row0 * Kd + ko + k0;
            a0 = *(const bf16x8*)A0;
            a1 = *(const bf16x8*)(A0 + strA);
        }
        bf16x8 b0 = *(const bf16x8*)(B0 + k0);
        bf16x8 b1 = *(const bf16x8*)(B0 + strA + k0);
        acc00 = __builtin_amdgcn_mfma_f32_16x16x32_bf16(b0, a0, acc00, 0, 0, 0);
        acc01 = __builtin_amdgcn_mfma_f32_16x16x32_bf16(b1, a0, acc01, 0, 0, 0);
        acc10 = __builtin_amdgcn_mfma_f32_16x16x32_bf16(b0, a1, acc10, 0, 0, 0);
        acc11 = __builtin_amdgcn_mfma_f32_16x16x32_bf16(b1, a1, acc11, 0, 0, 0);
    }
    const int r = lane & 15;
    const int c4 = (lane >> 4) << 2;
#pragma unroll
    for (int tm = 0; tm < 2; ++tm) {
        const int row = bm + tm * 16 + r;
        const size_t basep = (size_t)row * Nc;
        const f32x4 aL = tm ? acc10 : acc00;
        const f32x4 aR = tm ? acc11 : acc01;
#pragma unroll
        for (int tn = 0; tn < 2; ++tn) {
            const f32x4 a = tn ? aR : aL;
            const int c = bn + tn * 16 + c4;
            *(ushort4*)&Hb[basep + c] = make_ushort4(f2bf(a[0]), f2bf(a[1]),
                                                     f2bf(a[2]), f2bf(a[3]));
        }
    }
}

// ---------------- f32 fallback matmul ----------------
#define BM 64
#define BNT 64
#define BKT 16
__global__ __launch_bounds__(256) void k_mm(const float* __restrict__ A,
                                            const float* __restrict__ W,
                                            float* __restrict__ H, int Kd, int Nc) {
    __shared__ float As[BM][BKT + 1];
    __shared__ float Bs[BKT][BNT + 1];
    const int bm = blockIdx.x * BM;
    const int bn = blockIdx.y * BNT;
    const int tid = threadIdx.x;
    const int tx = tid & 15, ty = tid >> 4;
    float acc[4][4] = {};
    for (int k0 = 0; k0 < Kd; k0 += BKT) {
        for (int t = 0; t < 4; ++t) {
            int i = tid + t * 256;
            int m = i >> 4, k = i & 15;
            As[m][k] = (k0 + k < Kd) ? A[(size_t)(bm + m) * Kd + k0 + k] : 0.0f;
        }
        for (int t = 0; t < 4; ++t) {
            int i = tid + t * 256;
            int k = i >> 6, n = i & 63;
            Bs[k][n] = (k0 + k < Kd) ? W[(size_t)(k0 + k) * Nc + bn + n] : 0.0f;
        }
        __syncthreads();
        for (int k = 0; k < BKT; ++k) {
            float a[4], b[4];
#pragma unroll
            for (int i = 0; i < 4; ++i) a[i] = As[ty * 4 + i][k];
#pragma unroll
            for (int j = 0; j < 4; ++j) b[j] = Bs[k][tx * 4 + j];
#pragma unroll
            for (int i = 0; i < 4; ++i)
#pragma unroll
                for (int j = 0; j < 4; ++j) acc[i][j] += a[i] * b[j];
        }
        __syncthreads();
    }
#pragma unroll
    for (int i = 0; i < 4; ++i)
        *(float4*)&H[(size_t)(bm + ty * 4 + i) * Nc + bn + tx * 4] =
            make_float4(acc[i][0], acc[i][1], acc[i][2], acc[i][3]);
}

// ---------------- fused: Y = H*inv + bias + CSR-gather; per-chunk BN partials ----------------
// H source: bf16 Hb (mfma path) or f32 Hf (fallback). block = (16-row chunk) x channel slab.
#define BN1_ROWS 16
#define BN1_CHUNKS (NN / BN1_ROWS)   // 512
__global__ __launch_bounds__(256) void k_gfuse(const unsigned short* __restrict__ Hb,
                                               const float* __restrict__ Hf,
                                               const int* __restrict__ rowptr,
                                               const int* __restrict__ col,
                                               const float* __restrict__ ew,
                                               const int* __restrict__ deg,
                                               const float* __restrict__ bias,
                                               float* __restrict__ Y,
                                               float* __restrict__ psum,
                                               float* __restrict__ psq, int Nc) {
    __shared__ float4 ls[256], lq[256];
    const int CHB = (Nc < 128) ? Nc : 128;
    const int CB = Nc / CHB;
    const int chunk = blockIdx.x / CB;
    const int cb = blockIdx.x - chunk * CB;
    const int QPB = CHB >> 2;
    const int tid = threadIdx.x;
    const int q = tid & (QPB - 1);
    const int rg = tid / QPB;
    const int NRG = 256 / QPB;
    const int RPT = BN1_ROWS / NRG;
    const int c = cb * CHB + (q << 2);
    const float4 b4 = *(const float4*)&bias[c];
    float4 s4 = make_float4(0, 0, 0, 0), q4 = make_float4(0, 0, 0, 0);
    for (int rr = 0; rr < RPT; ++rr) {
        const int n = chunk * BN1_ROWS + rg * RPT + rr;
        const int j0 = rowptr[n], j1 = rowptr[n + 1];
        const float inv = 1.0f / (float)(deg[n] + 1);
        float4 acc;
        if (Hb) {
            ushort4 hv = *(const ushort4*)&Hb[(size_t)n * Nc + c];
            acc = make_float4(bf2f(hv.x), bf2f(hv.y), bf2f(hv.z), bf2f(hv.w));
        } else {
            acc = *(const float4*)&Hf[(size_t)n * Nc + c];
        }
        acc.x = acc.x * inv + b4.x;
        acc.y = acc.y * inv + b4.y;
        acc.z = acc.z * inv + b4.z;
        acc.w = acc.w * inv + b4.w;
        if (Hb) {
            for (int j = j0; j < j1; ++j) {
                const float w = ew[j];
                ushort4 hv = *(const ushort4*)&Hb[(size_t)col[j] * Nc + c];
                acc.x += bf2f(hv.x) * w; acc.y += bf2f(hv.y) * w;
                acc.z += bf2f(hv.z) * w; acc.w += bf2f(hv.w) * w;
            }
        } else {
            for (int j = j0; j < j1; ++j) {
                const float w = ew[j];
                const float4 hv = *(const float4*)&Hf[(size_t)col[j] * Nc + c];
                acc.x += hv.x * w; acc.y += hv.y * w; acc.z += hv.z * w; acc.w += hv.w * w;
            }
        }
        *(float4*)&Y[(size_t)n * Nc + c] = acc;
        s4.x += acc.x; s4.y += acc.y; s4.z += acc.z; s4.w += acc.w;
        q4.x += acc.x * acc.x; q4.y += acc.y * acc.y;
        q4.z += acc.z * acc.z; q4.w += acc.w * acc.w;
    }
    ls[tid] = s4; lq[tid] = q4;
    __syncthreads();
    for (int st = 128; st >= QPB; st >>= 1) {
        if (tid < st) {
            float4 a = ls[tid], b = ls[tid + st];
            ls[tid] = make_float4(a.x + b.x, a.y + b.y, a.z + b.z, a.w + b.w);
            float4 e = lq[tid], f = lq[tid + st];
            lq[tid] = make_float4(e.x + f.x, e.y + f.y, e.z + f.z, e.w + f.w);
        }
        __syncthreads();
    }
    if (tid < QPB) {
        *(float4*)&psum[(size_t)chunk * Nc + c] = ls[tid];
        *(float4*)&psq[(size_t)chunk * Nc + c] = lq[tid];
    }
}

// ---------------- BN stats stage 2: one block per channel ----------------
__global__ __launch_bounds__(256) void k_bn2p(const float* __restrict__ psum,
                                              const float* __restrict__ psq,
                                              const float* __restrict__ g,
                                              const float* __restrict__ be,
                                              float* __restrict__ scale,
                                              float* __restrict__ shift, int Nc) {
    __shared__ float ss[256], sq[256];
    const int c = blockIdx.x;
    const int t = threadIdx.x;
    float s = 0.0f, q = 0.0f;
    for (int b = t; b < BN1_CHUNKS; b += 256) {
        s += psum[(size_t)b * Nc + c];
        q += psq[(size_t)b * Nc + c];
    }
    ss[t] = s; sq[t] = q;
    __syncthreads();
    for (int st = 128; st > 0; st >>= 1) {
        if (t < st) { ss[t] += ss[t + st]; sq[t] += sq[t + st]; }
        __syncthreads();
    }
    if (t == 0) {
        double mean = (double)ss[0] / 8192.0;
        double var = (double)sq[0] / 8192.0 - mean * mean;
        float sc = (float)((double)g[c] / sqrt(var + 1e-5));
        scale[c] = sc;
        shift[c] = be[c] - (float)mean * sc;
    }
}

// f32 fallback bn-apply
__global__ void k_bnapply(float* x, const float* __restrict__ scale,
                          const float* __restrict__ shift, int Nc) {
    int i = blockIdx.x * blockDim.x + threadIdx.x;
    int c4 = i & ((Nc >> 2) - 1);
    float4 v = ((const float4*)x)[i];
    float4 sc = ((const float4*)scale)[c4];
    float4 sh = ((const float4*)shift)[c4];
    v.x = fmaxf(v.x * sc.x + sh.x, 0.0f);
    v.y = fmaxf(v.y * sc.y + sh.y, 0.0f);
    v.z = fmaxf(v.z * sc.z + sh.z, 0.0f);
    v.w = fmaxf(v.w * sc.w + sh.w, 0.0f);
    ((float4*)x)[i] = v;
}

// ---------------- pool stage A with fused BN+relu (reads Y f32) ----------------
#define PR 32
__global__ __launch_bounds__(256) void k_pool_af(const float* __restrict__ Y,
                                                 const float* __restrict__ scale,
                                                 const float* __restrict__ shift,
                                                 float* __restrict__ part) {
    __shared__ float4 red[128];
    const int g = blockIdx.x >> 5;
    const int rs = blockIdx.x & 31;
    const int half = threadIdx.x >> 7;
    const int q = threadIdx.x & 127;
    const float4 sc = *(const float4*)&scale[4 * q];
    const float4 sh = *(const float4*)&shift[4 * q];
    const float* xp = Y + (size_t)(g * KK + rs * PR + half * 16) * 512 + 4 * q;
    float4 s = make_float4(0, 0, 0, 0);
#pragma unroll
    for (int rr = 0; rr < 16; ++rr) {
        float4 v = *(const float4*)(xp + (size_t)rr * 512);
        s.x += fmaxf(v.x * sc.x + sh.x, 0.0f);
        s.y += fmaxf(v.y * sc.y + sh.y, 0.0f);
        s.z += fmaxf(v.z * sc.z + sh.z, 0.0f);
        s.w += fmaxf(v.w * sc.w + sh.w, 0.0f);
    }
    if (half == 1) red[q] = s;
    __syncthreads();
    if (half == 0) {
        float4 t = red[q];
        s.x += t.x; s.y += t.y; s.z += t.z; s.w += t.w;
        *(float4*)&part[(size_t)blockIdx.x * 512 + 4 * q] = s;
    }
}

// f32 fallback pool (x already BN-applied)
__global__ __launch_bounds__(256) void k_pool(const float* __restrict__ x, float* pooled) {
    __shared__ float red[4][64];
    int g = blockIdx.x >> 3;
    int c0 = (blockIdx.x & 7) * 64;
    int c = threadIdx.x & 63;
    int rp = threadIdx.x >> 6;
    float s = 0;
    for (int r = rp; r < KK; r += 4)
        s += x[(size_t)(g * KK + r) * 512 + c0 + c];
    red[rp][c] = s;
    __syncthreads();
    if (rp == 0)
        pooled[g * 512 + c0 + c] = red[0][c] + red[1][c] + red[2][c] + red[3][c];
}

// ---------------- FC1 k-split: grid (8 graphs, 16 slices of 32 k) ----------------
__global__ __launch_bounds__(256) void k_fc1s(const float* __restrict__ part,
                                              const float* __restrict__ fw1,
                                              float* __restrict__ part2) {
    __shared__ float pooled_s[32];
    __shared__ float red[256];
    const int g = blockIdx.x, s = blockIdx.y, tid = threadIdx.x;
    const int j = tid & 31;   // k within slice
    const int i = tid >> 5;   // 0..7
    float p = 0;
    for (int a = i; a < 32; a += 8)
        p += part[(size_t)(g * 32 + a) * 512 + 32 * s + j];
    red[tid] = p;
    __syncthreads();
    if (tid < 32) {
        float t = red[tid];
        for (int i2 = 1; i2 < 8; ++i2) t += red[i2 * 32 + tid];
        pooled_s[tid] = t;
    }
    __syncthreads();
    float acc = 0;
    const float* wp = fw1 + (size_t)(32 * s) * 256 + tid;
#pragma unroll
    for (int k = 0; k < 32; ++k) acc += pooled_s[k] * wp[k * 256];
    part2[(size_t)(g * 16 + s) * 256 + tid] = acc;
}

// ---------------- FC2 k-split: grid (8 graphs, 8 slices of 32 k) ----------------
__global__ __launch_bounds__(256) void k_fc2s(const float* __restrict__ part2,
                                              const float* __restrict__ fb1,
                                              const float* __restrict__ fw2,
                                              float* __restrict__ part3) {
    __shared__ float t1s[256];
    const int g = blockIdx.x, s = blockIdx.y, tid = threadIdx.x;
    float a1 = fb1[tid];
    for (int i = 0; i < 16; ++i) a1 += part2[(size_t)(g * 16 + i) * 256 + tid];
    t1s[tid] = fmaxf(a1, 0.0f);
    __syncthreads();
    float acc = 0;
    const float* wp = fw2 + (size_t)(32 * s) * 256 + tid;
#pragma unroll
    for (int k = 0; k < 32; ++k) acc += t1s[32 * s + k] * wp[k * 256];
    part3[(size_t)(g * 8 + s) * 256 + tid] = acc;
}

// ---------------- FC3 + log_softmax: 8 blocks ----------------
__global__ __launch_bounds__(256) void k_fc3f(const float* __restrict__ part3,
                                              const float* __restrict__ fb2,
                                              const float* __restrict__ fw3,
                                              const float* __restrict__ fb3,
                                              float* __restrict__ out) {
    __shared__ float t2s[256];
    __shared__ float red[256];
    __shared__ float logits[100];
    const int g = blockIdx.x, tid = threadIdx.x;
    float a2 = fb2[tid];
    for (int i = 0; i < 8; ++i) a2 += part3[(size_t)(g * 8 + i) * 256 + tid];
    t2s[tid] = fmaxf(a2, 0.0f);
    __syncthreads();
    float v = -INFINITY;
    if (tid < 100) {
        float a3 = fb3[tid];
        for (int k = 0; k < 256; ++k) a3 += t2s[k] * fw3[k * 100 + tid];
        logits[tid] = a3;
        v = a3;
    }
    red[tid] = v;
    __syncthreads();
    for (int s = 128; s > 0; s >>= 1) {
        if (tid < s) red[tid] = fmaxf(red[tid], red[tid + s]);
        __syncthreads();
    }
    float mx = red[0];
    __syncthreads();
    red[tid] = (tid < 100) ? expf(logits[tid] - mx) : 0.0f;
    __syncthreads();
    for (int s = 128; s > 0; s >>= 1) {
        if (tid < s) red[tid] += red[tid + s];
        __syncthreads();
    }
    float lse = logf(red[0]);
    if (tid < 100) out[g * 100 + tid] = logits[tid] - mx - lse;
}

// plain FC + relu (fallback path)
__global__ void k_fc(const float* __restrict__ in, const float* __restrict__ W,
                     const float* __restrict__ bias, float* out, int fi, int fo) {
    __shared__ float row[512];
    int g = blockIdx.x, tid = threadIdx.x;
    for (int k = tid; k < fi; k += blockDim.x) row[k] = in[g * fi + k];
    __syncthreads();
    if (tid < fo) {
        float acc = bias[tid];
        for (int k = 0; k < fi; ++k) acc += row[k] * W[k * fo + tid];
        out[g * fo + tid] = acc > 0.0f ? acc : 0.0f;
    }
}

// fallback FC2+FC3+log_softmax
__global__ __launch_bounds__(256) void k_fc23(const float* __restrict__ t1,
                                              const float* __restrict__ fw2,
                                              const float* __restrict__ fb2,
                                              const float* __restrict__ fw3,
                                              const float* __restrict__ fb3,
                                              float* __restrict__ out) {
    __shared__ float row[256];
    __shared__ float t2s[256];
    __shared__ float red[256];
    __shared__ float logits[100];
    const int g = blockIdx.x, tid = threadIdx.x;
    row[tid] = t1[g * 256 + tid];
    __syncthreads();
    float acc = fb2[tid];
    for (int k = 0; k < 256; ++k) acc += row[k] * fw2[k * 256 + tid];
    t2s[tid] = acc > 0.0f ? acc : 0.0f;
    __syncthreads();
    float v = -INFINITY;
    if (tid < 100) {
        float a3 = fb3[tid];
        for (int k = 0; k < 256; ++k) a3 += t2s[k] * fw3[k * 100 + tid];
        logits[tid] = a3;
        v = a3;
    }
    red[tid] = v;
    __syncthreads();
    for (int s = 128; s > 0; s >>= 1) {
        if (tid < s) red[tid] = fmaxf(red[tid], red[tid + s]);
        __syncthreads();
    }
    float mx = red[0];
    __syncthreads();
    red[tid] = (tid < 100) ? expf(logits[tid] - mx) : 0.0f;
    __syncthreads();
    for (int s = 128; s > 0; s >>= 1) {
        if (tid < s) red[tid] += red[tid + s];
        __syncthreads();
    }
    float lse = logf(red[0]);
    if (tid < 100) out[g * 100 + tid] = logits[tid] - mx - lse;
}

// ---------------- launch ----------------
extern "C" void kernel_launch(void* const* d_in, const int* in_sizes, int n_in,
                              void* d_out, int out_size, void* d_ws, size_t ws_size,
                              hipStream_t stream) {
    const float* pos = (const float*)d_in[0];
    const int* ei = (const int*)d_in[1];
    const float* p = (const float*)d_in[3];
    const float *W[5], *bb[5], *gg[5], *be[5];
    for (int i = 0; i < 5; ++i) {
        W[i]  = (const float*)d_in[4 + 4 * i];
        bb[i] = (const float*)d_in[5 + 4 * i];
        gg[i] = (const float*)d_in[6 + 4 * i];
        be[i] = (const float*)d_in[7 + 4 * i];
    }
    const float* fw1 = (const float*)d_in[24]; const float* fb1 = (const float*)d_in[25];
    const float* fw2 = (const float*)d_in[26]; const float* fb2 = (const float*)d_in[27];
    const float* fw3 = (const float*)d_in[28]; const float* fb3 = (const float*)d_in[29];
    float* out = (float*)d_out;

    const int fins[5]  = {3, 64, 128, 128, 256};
    const int kpads[5] = {32, 64, 128, 128, 256};
    const int fouts[5] = {64, 128, 128, 256, 512};

    size_t off = 0;
    char* base = (char*)d_ws;
    auto alloc = [&](size_t bytes) { char* q = base + off; off += (bytes + 255) & ~(size_t)255; return q; };

    float* Y      = (float*)alloc((size_t)NN * 512 * 4);
    float* Hf     = (float*)alloc((size_t)NN * 512 * 4);   // f32 fallback H; bf16 Hb aliases
    int*   remap  = (int*)alloc((size_t)NTOT * 4);
    int*   deg    = (int*)alloc(NN * 4);
    int*   cursor = (int*)alloc(NN * 4);
    int*   rowptr = (int*)alloc((NN + 1) * 4);
    int*   ecol   = (int*)alloc((size_t)NE * 4);
    float* ew     = (float*)alloc((size_t)NE * 4);
    float* psum   = (float*)alloc((size_t)BN1_CHUNKS * 512 * 4);
    float* psq    = (float*)alloc((size_t)BN1_CHUNKS * 512 * 4);
    float* scale  = (float*)alloc(512 * 4);
    float* shift  = (float*)alloc(512 * 4);
    float* pooled = (float*)alloc(8 * 512 * 4);
    float* t1     = (float*)alloc(8 * 256 * 4);
    unsigned short* Ab0 = (unsigned short*)alloc((size_t)NN * 32 * 2);
    float* part   = (float*)alloc((size_t)256 * 512 * 4);
    float* part2  = (float*)alloc((size_t)8 * 16 * 256 * 4);
    float* part3  = (float*)alloc((size_t)8 * 8 * 256 * 4);
    unsigned short* WT[5];
    for (int l = 0; l < 5; ++l) WT[l] = (unsigned short*)alloc((size_t)fouts[l] * kpads[l] * 2);
    unsigned short* Hb = (unsigned short*)Hf;
    const bool mfma = (ws_size >= off);

    k_topk2<<<BGR, 1024, 0, stream>>>(pos, p, remap, Y, Ab0, deg, cursor);
    k_deg<<<NE / 256, 256, 0, stream>>>(ei, remap, deg);
    k_scan<<<1, 1024, 0, stream>>>(deg, rowptr);
    k_place2<<<NE / 256, 256, 0, stream>>>(ei, remap, deg, rowptr, cursor, ecol, ew);

    if (mfma) {
        k_wt_all<<<(190464 + 255) / 256, 256, 0, stream>>>(W[0], W[1], W[2], W[3], W[4],
                                                           WT[0], WT[1], WT[2], WT[3], WT[4]);
        for (int l = 0; l < 5; ++l) {
            int fo = fouts[l];
            dim3 mg(NN / 64, fo / 64);
            if (l == 0)
                k_mm2<<<mg, 256, 0, stream>>>(Ab0, nullptr, nullptr, nullptr,
                                              WT[l], Hb, kpads[l], fo);
            else
                k_mm2<<<mg, 256, 0, stream>>>(nullptr, Y, scale, shift,
                                              WT[l], Hb, kpads[l], fo);
            int cbs = (fo < 128) ? 1 : fo / 128;
            k_gfuse<<<BN1_CHUNKS * cbs, 256, 0, stream>>>(Hb, nullptr, rowptr, ecol, ew,
                                                          deg, bb[l], Y, psum, psq, fo);
            k_bn2p<<<fo, 256, 0, stream>>>(psum, psq, gg[l], be[l], scale, shift, fo);
        }
        k_pool_af<<<256, 256, 0, stream>>>(Y, scale, shift, part);
        k_fc1s<<<dim3(8, 16), 256, 0, stream>>>(part, fw1, part2);
        k_fc2s<<<dim3(8, 8), 256, 0, stream>>>(part2, fb1, fw2, part3);
        k_fc3f<<<8, 256, 0, stream>>>(part3, fb2, fw3, fb3, out);
    } else {
        for (int l = 0; l < 5; ++l) {
            int fi = fins[l], fo = fouts[l];
            dim3 mg(NN / BM, fo / BNT);
            k_mm<<<mg, 256, 0, stream>>>(Y, W[l], Hf, fi, fo);
            int cbs = (fo < 128) ? 1 : fo / 128;
            k_gfuse<<<BN1_CHUNKS * cbs, 256, 0, stream>>>(nullptr, Hf, rowptr, ecol, ew,
                                                          deg, bb[l], Y, psum, psq, fo);
            k_bn2p<<<fo, 256, 0, stream>>>(psum, psq, gg[l], be[l], scale, shift, fo);
            k_bnapply<<<(NN * fo) / 1024, 256, 0, stream>>>(Y, scale, shift, fo);
        }
        k_pool<<<64, 256, 0, stream>>>(Y, pooled);
        k_fc<<<8, 256, 0, stream>>>(pooled, fw1, fb1, t1, 512, 256);
        k_fc23<<<8, 256, 0, stream>>>(t1, fw2, fb2, fw3, fb3, out);
    }
}

// Round 14
// 175.749 us; speedup vs baseline: 1.8054x; 1.0475x over previous
//
#include <hip/hip_runtime.h>
#include <math.h>

#define NTOT 32768   // B*NP
#define NPG  4096    // nodes per graph
#define BGR  8       // graphs
#define KK   1024    // top-k
#define NN   8192    // B*K kept nodes
#define NE   262144  // edges

typedef __attribute__((ext_vector_type(8))) short bf16x8;
typedef __attribute__((ext_vector_type(4))) float f32x4;

static __device__ __forceinline__ unsigned short f2bf(float f) {
    unsigned u = __float_as_uint(f);
    return (unsigned short)((u + 0x7fffu + ((u >> 16) & 1u)) >> 16);
}
static __device__ __forceinline__ float bf2f(unsigned short b) {
    return __uint_as_float(((unsigned)b) << 16);
}

// ---------------- top-k per graph: radix select + ordered compaction ----------------
// Also initializes remap (its graph's 4096 nodes) and zeroes deg/cursor slice.
__global__ __launch_bounds__(1024) void k_topk2(const float* __restrict__ pos,
                                                const float* __restrict__ p,
                                                int* __restrict__ remap,
                                                float* __restrict__ x0f,
                                                unsigned short* __restrict__ Ab0,
                                                int* __restrict__ deg,
                                                int* __restrict__ cursor) {
    __shared__ unsigned skey[NPG];
    __shared__ float sval[NPG];
    __shared__ int hist[256];
    __shared__ int Sarr[256];
    __shared__ int wsum[16];
    __shared__ int s_bin, s_above;

    const int g = blockIdx.x, tid = threadIdx.x;
    const int lane = tid & 63, wid = tid >> 6;
    deg[g * KK + tid] = 0;
    cursor[g * KK + tid] = 0;
    const float p0 = p[0], p1 = p[1], p2 = p[2];
    const float invn = 1.0f / sqrtf(p0 * p0 + p1 * p1 + p2 * p2);

    for (int i = tid; i < NPG; i += 1024) {
        const float* pp = pos + (size_t)(g * NPG + i) * 3;
        float s = tanhf((pp[0] * p0 + pp[1] * p1 + pp[2] * p2) * invn);
        sval[i] = s;
        unsigned b = __float_as_uint(s);
        skey[i] = (b & 0x80000000u) ? ~b : (b | 0x80000000u);
    }
    __syncthreads();

    unsigned prefix = 0;
    int needed = KK;
    for (int r = 0; r < 4; ++r) {
        const int sh = 24 - 8 * r;
        if (tid < 256) hist[tid] = 0;
        __syncthreads();
        for (int i = tid; i < NPG; i += 1024) {
            unsigned k = skey[i];
            bool act = (r == 0) || ((k >> (sh + 8)) == prefix);
            if (act) atomicAdd(&hist[(k >> sh) & 255u], 1);
        }
        __syncthreads();
        if (wid == 0) {
            int h0 = hist[4 * lane + 0], h1 = hist[4 * lane + 1];
            int h2 = hist[4 * lane + 2], h3 = hist[4 * lane + 3];
            int l3 = h3, l2 = h2 + l3, l1 = h1 + l2, l0 = h0 + l1;
            int t = l0;
            for (int off = 1; off < 64; off <<= 1) {
                int n = __shfl_down(t, off, 64);
                if (lane + off < 64) t += n;
            }
            int hi = t - l0;
            Sarr[4 * lane + 0] = l0 + hi;
            Sarr[4 * lane + 1] = l1 + hi;
            Sarr[4 * lane + 2] = l2 + hi;
            Sarr[4 * lane + 3] = l3 + hi;
        }
        __syncthreads();
        if (tid < 256) {
            int Sb = Sarr[tid];
            int Sb1 = (tid < 255) ? Sarr[tid + 1] : 0;
            if (Sb >= needed && Sb1 < needed) { s_bin = tid; s_above = Sb1; }
        }
        __syncthreads();
        needed -= s_above;
        prefix = (prefix << 8) | (unsigned)s_bin;
        __syncthreads();
    }
    const unsigned Tkey = prefix;
    const int needTies = needed;

    int tiebase = 0, keepbase = 0;
    for (int c = 0; c < 4; ++c) {
        const int i = c * 1024 + tid;
        const unsigned k = skey[i];
        const int tie = (k == Tkey) ? 1 : 0;
        int v = tie;
        for (int off = 1; off < 64; off <<= 1) {
            int n = __shfl_up(v, off, 64);
            if (lane >= off) v += n;
        }
        if (lane == 63) wsum[wid] = v;
        __syncthreads();
        if (wid == 0) {
            int w = (lane < 16) ? wsum[lane] : 0;
            for (int off = 1; off < 16; off <<= 1) {
                int n = __shfl_up(w, off, 64);
                if (lane >= off) w += n;
            }
            if (lane < 16) wsum[lane] = w;
        }
        __syncthreads();
        const int trank = tiebase + v + (wid > 0 ? wsum[wid - 1] : 0) - tie;
        const int ttot = wsum[15];
        const int keep = (k > Tkey) || (tie && trank < needTies);
        __syncthreads();
        int u = keep;
        for (int off = 1; off < 64; off <<= 1) {
            int n = __shfl_up(u, off, 64);
            if (lane >= off) u += n;
        }
        if (lane == 63) wsum[wid] = u;
        __syncthreads();
        if (wid == 0) {
            int w = (lane < 16) ? wsum[lane] : 0;
            for (int off = 1; off < 16; off <<= 1) {
                int n = __shfl_up(w, off, 64);
                if (lane >= off) w += n;
            }
            if (lane < 16) wsum[lane] = w;
        }
        __syncthreads();
        const int kincl = u + (wid > 0 ? wsum[wid - 1] : 0);
        const int ktot = wsum[15];
        if (keep) {
            int nn = g * KK + keepbase + kincl - 1;
            remap[g * NPG + i] = nn;
            float val = sval[i];
            const float* pp = pos + (size_t)(g * NPG + i) * 3;
            float v0 = pp[0] * val, v1 = pp[1] * val, v2 = pp[2] * val;
            x0f[(size_t)nn * 3 + 0] = v0;
            x0f[(size_t)nn * 3 + 1] = v1;
            x0f[(size_t)nn * 3 + 2] = v2;
            unsigned short* rw = Ab0 + (size_t)nn * 32;
            ushort4 a = make_ushort4(f2bf(v0), f2bf(v1), f2bf(v2), 0);
            ushort4 z = make_ushort4(0, 0, 0, 0);
            *(ushort4*)(rw) = a;
#pragma unroll
            for (int t = 1; t < 8; ++t) *(ushort4*)(rw + 4 * t) = z;
        } else {
            remap[g * NPG + i] = -1;
        }
        tiebase += ttot;
        keepbase += ktot;
        __syncthreads();
    }
}

// ---------------- pass 1: in-degree ----------------
__global__ void k_deg(const int* __restrict__ ei, const int* __restrict__ remap,
                      int* __restrict__ deg) {
    int e = blockIdx.x * blockDim.x + threadIdx.x;
    if (e >= NE) return;
    int s = remap[ei[e]];
    int d = remap[ei[NE + e]];
    if (s >= 0 && d >= 0) atomicAdd(&deg[d], 1);
}

// ---------------- exclusive scan of deg -> rowptr ----------------
__global__ __launch_bounds__(1024) void k_scan(const int* __restrict__ deg,
                                               int* __restrict__ rowptr) {
    __shared__ int part[1024];
    const int tid = threadIdx.x;
    const int base = tid * 8;
    int loc[8];
    int s = 0;
#pragma unroll
    for (int i = 0; i < 8; ++i) { loc[i] = s; s += deg[base + i]; }
    part[tid] = s;
    __syncthreads();
    for (int off = 1; off < 1024; off <<= 1) {
        int v = (tid >= off) ? part[tid - off] : 0;
        __syncthreads();
        part[tid] += v;
        __syncthreads();
    }
    int pre = (tid > 0) ? part[tid - 1] : 0;
#pragma unroll
    for (int i = 0; i < 8; ++i) rowptr[base + i] = pre + loc[i];
    if (tid == 1023) rowptr[NN] = pre + s;
}

// ---------------- pass 2: place edges into CSR (by dst) ----------------
__global__ void k_place2(const int* __restrict__ ei, const int* __restrict__ remap,
                         const int* __restrict__ deg, const int* __restrict__ rowptr,
                         int* __restrict__ cursor, int* __restrict__ col,
                         float* __restrict__ ew) {
    int e = blockIdx.x * blockDim.x + threadIdx.x;
    if (e >= NE) return;
    int s = remap[ei[e]];
    int d = remap[ei[NE + e]];
    if (s >= 0 && d >= 0) {
        int pos = rowptr[d] + atomicAdd(&cursor[d], 1);
        col[pos] = s;
        ew[pos] = rsqrtf((float)(deg[s] + 1)) * rsqrtf((float)(deg[d] + 1));
    }
}

// ---------------- all weights transpose + bf16 convert, one launch ----------------
__global__ void k_wt_all(const float* __restrict__ w0, const float* __restrict__ w1,
                         const float* __restrict__ w2, const float* __restrict__ w3,
                         const float* __restrict__ w4,
                         unsigned short* __restrict__ t0, unsigned short* __restrict__ t1,
                         unsigned short* __restrict__ t2, unsigned short* __restrict__ t3,
                         unsigned short* __restrict__ t4) {
    int i = blockIdx.x * blockDim.x + threadIdx.x;
    const float* W; unsigned short* T; int Kd, Nc, Kpad, base;
    if (i < 2048)        { W = w0; T = t0; Kd = 3;   Nc = 64;  Kpad = 32;  base = 0; }
    else if (i < 10240)  { W = w1; T = t1; Kd = 64;  Nc = 128; Kpad = 64;  base = 2048; }
    else if (i < 26624)  { W = w2; T = t2; Kd = 128; Nc = 128; Kpad = 128; base = 10240; }
    else if (i < 59392)  { W = w3; T = t3; Kd = 128; Nc = 256; Kpad = 128; base = 26624; }
    else if (i < 190464) { W = w4; T = t4; Kd = 256; Nc = 512; Kpad = 256; base = 59392; }
    else return;
    int j = i - base;
    int n = j / Kpad, k = j - n * Kpad;
    float v = (k < Kd) ? W[(size_t)k * Nc + n] : 0.0f;
    T[j] = f2bf(v);
}

// ---------------- MFMA bf16 GEMM: Hb = bf16(A @ W)  [verified shape, layers 1-4] ----------------
__global__ __launch_bounds__(256) void k_mm2(const unsigned short* __restrict__ Ab,
                                             const float* __restrict__ Yin,
                                             const float* __restrict__ scale,
                                             const float* __restrict__ shift,
                                             const unsigned short* __restrict__ WT,
                                             unsigned short* __restrict__ Hb,
                                             int Kd, int Nc) {
    const int lane = threadIdx.x & 63, wid = threadIdx.x >> 6;
    const int bm = blockIdx.x * 64 + (wid >> 1) * 32;
    const int bn = blockIdx.y * 64 + (wid & 1) * 32;
    const int fr = lane & 15;
    const int ko = (lane >> 4) << 3;
    const int row0 = bm + fr;
    const unsigned short* B0 = WT + (size_t)(bn + fr) * Kd + ko;
    const size_t strA = (size_t)16 * Kd;
    f32x4 acc00 = {0,0,0,0}, acc01 = {0,0,0,0}, acc10 = {0,0,0,0}, acc11 = {0,0,0,0};
    for (int k0 = 0; k0 < Kd; k0 += 32) {
        bf16x8 a0, a1;
        if (Yin) {
            const int cc = ko + k0;
            const float4 sc0 = *(const float4*)&scale[cc];
            const float4 sc1 = *(const float4*)&scale[cc + 4];
            const float4 sh0 = *(const float4*)&shift[cc];
            const float4 sh1 = *(const float4*)&shift[cc + 4];
            const float* y0 = Yin + (size_t)row0 * Kd + cc;
            const float* y1 = y0 + strA;
#pragma unroll
            for (int h = 0; h < 2; ++h) {
                const float* yy = h ? y1 : y0;
                float4 u = *(const float4*)yy;
                float4 v = *(const float4*)(yy + 4);
                bf16x8 a;
                a[0] = (short)f2bf(fmaxf(u.x * sc0.x + sh0.x, 0.0f));
                a[1] = (short)f2bf(fmaxf(u.y * sc0.y + sh0.y, 0.0f));
                a[2] = (short)f2bf(fmaxf(u.z * sc0.z + sh0.z, 0.0f));
                a[3] = (short)f2bf(fmaxf(u.w * sc0.w + sh0.w, 0.0f));
                a[4] = (short)f2bf(fmaxf(v.x * sc1.x + sh1.x, 0.0f));
                a[5] = (short)f2bf(fmaxf(v.y * sc1.y + sh1.y, 0.0f));
                a[6] = (short)f2bf(fmaxf(v.z * sc1.z + sh1.z, 0.0f));
                a[7] = (short)f2bf(fmaxf(v.w * sc1.w + sh1.w, 0.0f));
                if (h) a1 = a; else a0 = a;
            }
        } else {
            const unsigned short* A0 = Ab + (size_t)row0 * Kd + ko + k0;
            a0 = *(const bf16x8*)A0;
            a1 = *(const bf16x8*)(A0 + strA);
        }
        bf16x8 b0 = *(const bf16x8*)(B0 + k0);
        bf16x8 b1 = *(const bf16x8*)(B0 + strA + k0);
        acc00 = __builtin_amdgcn_mfma_f32_16x16x32_bf16(b0, a0, acc00, 0, 0, 0);
        acc01 = __builtin_amdgcn_mfma_f32_16x16x32_bf16(b1, a0, acc01, 0, 0, 0);
        acc10 = __builtin_amdgcn_mfma_f32_16x16x32_bf16(b0, a1, acc10, 0, 0, 0);
        acc11 = __builtin_amdgcn_mfma_f32_16x16x32_bf16(b1, a1, acc11, 0, 0, 0);
    }
    const int r = lane & 15;
    const int c4 = (lane >> 4) << 2;
#pragma unroll
    for (int tm = 0; tm < 2; ++tm) {
        const int row = bm + tm * 16 + r;
        const size_t basep = (size_t)row * Nc;
        const f32x4 aL = tm ? acc10 : acc00;
        const f32x4 aR = tm ? acc11 : acc01;
#pragma unroll
        for (int tn = 0; tn < 2; ++tn) {
            const f32x4 a = tn ? aR : aL;
            const int c = bn + tn * 16 + c4;
            *(ushort4*)&Hb[basep + c] = make_ushort4(f2bf(a[0]), f2bf(a[1]),
                                                     f2bf(a[2]), f2bf(a[3]));
        }
    }
}

// ---------------- wide variant for fo=512: 2 column tiles per block ----------------
// Grid (NN/64, Nc/128). A fragments loaded once per k-step feed both column tiles:
// halves the Yin re-read multiplier (8 -> 4 col-blocks) and the BN+cvt VALU work.
__global__ __launch_bounds__(256) void k_mm2w(const float* __restrict__ Yin,
                                              const float* __restrict__ scale,
                                              const float* __restrict__ shift,
                                              const unsigned short* __restrict__ WT,
                                              unsigned short* __restrict__ Hb,
                                              int Kd, int Nc) {
    const int lane = threadIdx.x & 63, wid = threadIdx.x >> 6;
    const int bm = blockIdx.x * 64 + (wid >> 1) * 32;
    const int bn = blockIdx.y * 128 + (wid & 1) * 32;   // second tile at bn+64
    const int fr = lane & 15;
    const int ko = (lane >> 4) << 3;
    const int row0 = bm + fr;
    const unsigned short* B0 = WT + (size_t)(bn + fr) * Kd + ko;
    const unsigned short* B2 = WT + (size_t)(bn + 64 + fr) * Kd + ko;
    const size_t strA = (size_t)16 * Kd;
    f32x4 acc00 = {0,0,0,0}, acc01 = {0,0,0,0}, acc10 = {0,0,0,0}, acc11 = {0,0,0,0};
    f32x4 acc20 = {0,0,0,0}, acc21 = {0,0,0,0}, acc30 = {0,0,0,0}, acc31 = {0,0,0,0};
    for (int k0 = 0; k0 < Kd; k0 += 32) {
        bf16x8 a0, a1;
        {
            const int cc = ko + k0;
            const float4 sc0 = *(const float4*)&scale[cc];
            const float4 sc1 = *(const float4*)&scale[cc + 4];
            const float4 sh0 = *(const float4*)&shift[cc];
            const float4 sh1 = *(const float4*)&shift[cc + 4];
            const float* y0 = Yin + (size_t)row0 * Kd + cc;
            const float* y1 = y0 + strA;
#pragma unroll
            for (int h = 0; h < 2; ++h) {
                const float* yy = h ? y1 : y0;
                float4 u = *(const float4*)yy;
                float4 v = *(const float4*)(yy + 4);
                bf16x8 a;
                a[0] = (short)f2bf(fmaxf(u.x * sc0.x + sh0.x, 0.0f));
                a[1] = (short)f2bf(fmaxf(u.y * sc0.y + sh0.y, 0.0f));
                a[2] = (short)f2bf(fmaxf(u.z * sc0.z + sh0.z, 0.0f));
                a[3] = (short)f2bf(fmaxf(u.w * sc0.w + sh0.w, 0.0f));
                a[4] = (short)f2bf(fmaxf(v.x * sc1.x + sh1.x, 0.0f));
                a[5] = (short)f2bf(fmaxf(v.y * sc1.y + sh1.y, 0.0f));
                a[6] = (short)f2bf(fmaxf(v.z * sc1.z + sh1.z, 0.0f));
                a[7] = (short)f2bf(fmaxf(v.w * sc1.w + sh1.w, 0.0f));
                if (h) a1 = a; else a0 = a;
            }
        }
        bf16x8 b0 = *(const bf16x8*)(B0 + k0);
        bf16x8 b1 = *(const bf16x8*)(B0 + strA + k0);
        bf16x8 b2 = *(const bf16x8*)(B2 + k0);
        bf16x8 b3 = *(const bf16x8*)(B2 + strA + k0);
        acc00 = __builtin_amdgcn_mfma_f32_16x16x32_bf16(b0, a0, acc00, 0, 0, 0);
        acc01 = __builtin_amdgcn_mfma_f32_16x16x32_bf16(b1, a0, acc01, 0, 0, 0);
        acc10 = __builtin_amdgcn_mfma_f32_16x16x32_bf16(b0, a1, acc10, 0, 0, 0);
        acc11 = __builtin_amdgcn_mfma_f32_16x16x32_bf16(b1, a1, acc11, 0, 0, 0);
        acc20 = __builtin_amdgcn_mfma_f32_16x16x32_bf16(b2, a0, acc20, 0, 0, 0);
        acc21 = __builtin_amdgcn_mfma_f32_16x16x32_bf16(b3, a0, acc21, 0, 0, 0);
        acc30 = __builtin_amdgcn_mfma_f32_16x16x32_bf16(b2, a1, acc30, 0, 0, 0);
        acc31 = __builtin_amdgcn_mfma_f32_16x16x32_bf16(b3, a1, acc31, 0, 0, 0);
    }
    const int r = lane & 15;
    const int c4 = (lane >> 4) << 2;
#pragma unroll
    for (int ct = 0; ct < 2; ++ct) {
#pragma unroll
        for (int tm = 0; tm < 2; ++tm) {
            const int row = bm + tm * 16 + r;
            const size_t basep = (size_t)row * Nc;
            f32x4 aL, aR;
            if (ct == 0) { aL = tm ? acc10 : acc00; aR = tm ? acc11 : acc01; }
            else         { aL = tm ? acc30 : acc20; aR = tm ? acc31 : acc21; }
#pragma unroll
            for (int tn = 0; tn < 2; ++tn) {
                const f32x4 a = tn ? aR : aL;
                const int c = bn + ct * 64 + tn * 16 + c4;
                *(ushort4*)&Hb[basep + c] = make_ushort4(f2bf(a[0]), f2bf(a[1]),
                                                         f2bf(a[2]), f2bf(a[3]));
            }
        }
    }
}

// ---------------- f32 fallback matmul ----------------
#define BM 64
#define BNT 64
#define BKT 16
__global__ __launch_bounds__(256) void k_mm(const float* __restrict__ A,
                                            const float* __restrict__ W,
                                            float* __restrict__ H, int Kd, int Nc) {
    __shared__ float As[BM][BKT + 1];
    __shared__ float Bs[BKT][BNT + 1];
    const int bm = blockIdx.x * BM;
    const int bn = blockIdx.y * BNT;
    const int tid = threadIdx.x;
    const int tx = tid & 15, ty = tid >> 4;
    float acc[4][4] = {};
    for (int k0 = 0; k0 < Kd; k0 += BKT) {
        for (int t = 0; t < 4; ++t) {
            int i = tid + t * 256;
            int m = i >> 4, k = i & 15;
            As[m][k] = (k0 + k < Kd) ? A[(size_t)(bm + m) * Kd + k0 + k] : 0.0f;
        }
        for (int t = 0; t < 4; ++t) {
            int i = tid + t * 256;
            int k = i >> 6, n = i & 63;
            Bs[k][n] = (k0 + k < Kd) ? W[(size_t)(k0 + k) * Nc + bn + n] : 0.0f;
        }
        __syncthreads();
        for (int k = 0; k < BKT; ++k) {
            float a[4], b[4];
#pragma unroll
            for (int i = 0; i < 4; ++i) a[i] = As[ty * 4 + i][k];
#pragma unroll
            for (int j = 0; j < 4; ++j) b[j] = Bs[k][tx * 4 + j];
#pragma unroll
            for (int i = 0; i < 4; ++i)
#pragma unroll
                for (int j = 0; j < 4; ++j) acc[i][j] += a[i] * b[j];
        }
        __syncthreads();
    }
#pragma unroll
    for (int i = 0; i < 4; ++i)
        *(float4*)&H[(size_t)(bm + ty * 4 + i) * Nc + bn + tx * 4] =
            make_float4(acc[i][0], acc[i][1], acc[i][2], acc[i][3]);
}

// ---------------- fused: Y = H*inv + bias + CSR-gather; per-chunk BN partials ----------------
#define BN1_ROWS 16
#define BN1_CHUNKS (NN / BN1_ROWS)   // 512
__global__ __launch_bounds__(256) void k_gfuse(const unsigned short* __restrict__ Hb,
                                               const float* __restrict__ Hf,
                                               const int* __restrict__ rowptr,
                                               const int* __restrict__ col,
                                               const float* __restrict__ ew,
                                               const int* __restrict__ deg,
                                               const float* __restrict__ bias,
                                               float* __restrict__ Y,
                                               float* __restrict__ psum,
                                               float* __restrict__ psq, int Nc) {
    __shared__ float4 ls[256], lq[256];
    const int CHB = (Nc < 128) ? Nc : 128;
    const int CB = Nc / CHB;
    const int chunk = blockIdx.x / CB;
    const int cb = blockIdx.x - chunk * CB;
    const int QPB = CHB >> 2;
    const int tid = threadIdx.x;
    const int q = tid & (QPB - 1);
    const int rg = tid / QPB;
    const int NRG = 256 / QPB;
    const int RPT = BN1_ROWS / NRG;
    const int c = cb * CHB + (q << 2);
    const float4 b4 = *(const float4*)&bias[c];
    float4 s4 = make_float4(0, 0, 0, 0), q4 = make_float4(0, 0, 0, 0);
    for (int rr = 0; rr < RPT; ++rr) {
        const int n = chunk * BN1_ROWS + rg * RPT + rr;
        const int j0 = rowptr[n], j1 = rowptr[n + 1];
        const float inv = 1.0f / (float)(deg[n] + 1);
        float4 acc;
        if (Hb) {
            ushort4 hv = *(const ushort4*)&Hb[(size_t)n * Nc + c];
            acc = make_float4(bf2f(hv.x), bf2f(hv.y), bf2f(hv.z), bf2f(hv.w));
        } else {
            acc = *(const float4*)&Hf[(size_t)n * Nc + c];
        }
        acc.x = acc.x * inv + b4.x;
        acc.y = acc.y * inv + b4.y;
        acc.z = acc.z * inv + b4.z;
        acc.w = acc.w * inv + b4.w;
        if (Hb) {
            for (int j = j0; j < j1; ++j) {
                const float w = ew[j];
                ushort4 hv = *(const ushort4*)&Hb[(size_t)col[j] * Nc + c];
                acc.x += bf2f(hv.x) * w; acc.y += bf2f(hv.y) * w;
                acc.z += bf2f(hv.z) * w; acc.w += bf2f(hv.w) * w;
            }
        } else {
            for (int j = j0; j < j1; ++j) {
                const float w = ew[j];
                const float4 hv = *(const float4*)&Hf[(size_t)col[j] * Nc + c];
                acc.x += hv.x * w; acc.y += hv.y * w; acc.z += hv.z * w; acc.w += hv.w * w;
            }
        }
        *(float4*)&Y[(size_t)n * Nc + c] = acc;
        s4.x += acc.x; s4.y += acc.y; s4.z += acc.z; s4.w += acc.w;
        q4.x += acc.x * acc.x; q4.y += acc.y * acc.y;
        q4.z += acc.z * acc.z; q4.w += acc.w * acc.w;
    }
    ls[tid] = s4; lq[tid] = q4;
    __syncthreads();
    for (int st = 128; st >= QPB; st >>= 1) {
        if (tid < st) {
            float4 a = ls[tid], b = ls[tid + st];
            ls[tid] = make_float4(a.x + b.x, a.y + b.y, a.z + b.z, a.w + b.w);
            float4 e = lq[tid], f = lq[tid + st];
            lq[tid] = make_float4(e.x + f.x, e.y + f.y, e.z + f.z, e.w + f.w);
        }
        __syncthreads();
    }
    if (tid < QPB) {
        *(float4*)&psum[(size_t)chunk * Nc + c] = ls[tid];
        *(float4*)&psq[(size_t)chunk * Nc + c] = lq[tid];
    }
}

// ---------------- BN stats stage 2: one block per channel ----------------
__global__ __launch_bounds__(256) void k_bn2p(const float* __restrict__ psum,
                                              const float* __restrict__ psq,
                                              const float* __restrict__ g,
                                              const float* __restrict__ be,
                                              float* __restrict__ scale,
                                              float* __restrict__ shift, int Nc) {
    __shared__ float ss[256], sq[256];
    const int c = blockIdx.x;
    const int t = threadIdx.x;
    float s = 0.0f, q = 0.0f;
    for (int b = t; b < BN1_CHUNKS; b += 256) {
        s += psum[(size_t)b * Nc + c];
        q += psq[(size_t)b * Nc + c];
    }
    ss[t] = s; sq[t] = q;
    __syncthreads();
    for (int st = 128; st > 0; st >>= 1) {
        if (t < st) { ss[t] += ss[t + st]; sq[t] += sq[t + st]; }
        __syncthreads();
    }
    if (t == 0) {
        double mean = (double)ss[0] / 8192.0;
        double var = (double)sq[0] / 8192.0 - mean * mean;
        float sc = (float)((double)g[c] / sqrt(var + 1e-5));
        scale[c] = sc;
        shift[c] = be[c] - (float)mean * sc;
    }
}

// f32 fallback bn-apply
__global__ void k_bnapply(float* x, const float* __restrict__ scale,
                          const float* __restrict__ shift, int Nc) {
    int i = blockIdx.x * blockDim.x + threadIdx.x;
    int c4 = i & ((Nc >> 2) - 1);
    float4 v = ((const float4*)x)[i];
    float4 sc = ((const float4*)scale)[c4];
    float4 sh = ((const float4*)shift)[c4];
    v.x = fmaxf(v.x * sc.x + sh.x, 0.0f);
    v.y = fmaxf(v.y * sc.y + sh.y, 0.0f);
    v.z = fmaxf(v.z * sc.z + sh.z, 0.0f);
    v.w = fmaxf(v.w * sc.w + sh.w, 0.0f);
    ((float4*)x)[i] = v;
}

// ---------------- pool stage A with fused BN+relu (reads Y f32) ----------------
#define PR 32
__global__ __launch_bounds__(256) void k_pool_af(const float* __restrict__ Y,
                                                 const float* __restrict__ scale,
                                                 const float* __restrict__ shift,
                                                 float* __restrict__ part) {
    __shared__ float4 red[128];
    const int g = blockIdx.x >> 5;
    const int rs = blockIdx.x & 31;
    const int half = threadIdx.x >> 7;
    const int q = threadIdx.x & 127;
    const float4 sc = *(const float4*)&scale[4 * q];
    const float4 sh = *(const float4*)&shift[4 * q];
    const float* xp = Y + (size_t)(g * KK + rs * PR + half * 16) * 512 + 4 * q;
    float4 s = make_float4(0, 0, 0, 0);
#pragma unroll
    for (int rr = 0; rr < 16; ++rr) {
        float4 v = *(const float4*)(xp + (size_t)rr * 512);
        s.x += fmaxf(v.x * sc.x + sh.x, 0.0f);
        s.y += fmaxf(v.y * sc.y + sh.y, 0.0f);
        s.z += fmaxf(v.z * sc.z + sh.z, 0.0f);
        s.w += fmaxf(v.w * sc.w + sh.w, 0.0f);
    }
    if (half == 1) red[q] = s;
    __syncthreads();
    if (half == 0) {
        float4 t = red[q];
        s.x += t.x; s.y += t.y; s.z += t.z; s.w += t.w;
        *(float4*)&part[(size_t)blockIdx.x * 512 + 4 * q] = s;
    }
}

// f32 fallback pool (x already BN-applied)
__global__ __launch_bounds__(256) void k_pool(const float* __restrict__ x, float* pooled) {
    __shared__ float red[4][64];
    int g = blockIdx.x >> 3;
    int c0 = (blockIdx.x & 7) * 64;
    int c = threadIdx.x & 63;
    int rp = threadIdx.x >> 6;
    float s = 0;
    for (int r = rp; r < KK; r += 4)
        s += x[(size_t)(g * KK + r) * 512 + c0 + c];
    red[rp][c] = s;
    __syncthreads();
    if (rp == 0)
        pooled[g * 512 + c0 + c] = red[0][c] + red[1][c] + red[2][c] + red[3][c];
}

// ---------------- FC1 k-split: grid (8 graphs, 16 slices of 32 k) ----------------
__global__ __launch_bounds__(256) void k_fc1s(const float* __restrict__ part,
                                              const float* __restrict__ fw1,
                                              float* __restrict__ part2) {
    __shared__ float pooled_s[32];
    __shared__ float red[256];
    const int g = blockIdx.x, s = blockIdx.y, tid = threadIdx.x;
    const int j = tid & 31;   // k within slice
    const int i = tid >> 5;   // 0..7
    float p = 0;
    for (int a = i; a < 32; a += 8)
        p += part[(size_t)(g * 32 + a) * 512 + 32 * s + j];
    red[tid] = p;
    __syncthreads();
    if (tid < 32) {
        float t = red[tid];
        for (int i2 = 1; i2 < 8; ++i2) t += red[i2 * 32 + tid];
        pooled_s[tid] = t;
    }
    __syncthreads();
    float acc = 0;
    const float* wp = fw1 + (size_t)(32 * s) * 256 + tid;
#pragma unroll
    for (int k = 0; k < 32; ++k) acc += pooled_s[k] * wp[k * 256];
    part2[(size_t)(g * 16 + s) * 256 + tid] = acc;
}

// ---------------- FC2 k-split: grid (8 graphs, 8 slices of 32 k) ----------------
__global__ __launch_bounds__(256) void k_fc2s(const float* __restrict__ part2,
                                              const float* __restrict__ fb1,
                                              const float* __restrict__ fw2,
                                              float* __restrict__ part3) {
    __shared__ float t1s[256];
    const int g = blockIdx.x, s = blockIdx.y, tid = threadIdx.x;
    float a1 = fb1[tid];
    for (int i = 0; i < 16; ++i) a1 += part2[(size_t)(g * 16 + i) * 256 + tid];
    t1s[tid] = fmaxf(a1, 0.0f);
    __syncthreads();
    float acc = 0;
    const float* wp = fw2 + (size_t)(32 * s) * 256 + tid;
#pragma unroll
    for (int k = 0; k < 32; ++k) acc += t1s[32 * s + k] * wp[k * 256];
    part3[(size_t)(g * 8 + s) * 256 + tid] = acc;
}

// ---------------- FC3 + log_softmax: 8 blocks ----------------
__global__ __launch_bounds__(256) void k_fc3f(const float* __restrict__ part3,
                                              const float* __restrict__ fb2,
                                              const float* __restrict__ fw3,
                                              const float* __restrict__ fb3,
                                              float* __restrict__ out) {
    __shared__ float t2s[256];
    __shared__ float red[256];
    __shared__ float logits[100];
    const int g = blockIdx.x, tid = threadIdx.x;
    float a2 = fb2[tid];
    for (int i = 0; i < 8; ++i) a2 += part3[(size_t)(g * 8 + i) * 256 + tid];
    t2s[tid] = fmaxf(a2, 0.0f);
    __syncthreads();
    float v = -INFINITY;
    if (tid < 100) {
        float a3 = fb3[tid];
        for (int k = 0; k < 256; ++k) a3 += t2s[k] * fw3[k * 100 + tid];
        logits[tid] = a3;
        v = a3;
    }
    red[tid] = v;
    __syncthreads();
    for (int s = 128; s > 0; s >>= 1) {
        if (tid < s) red[tid] = fmaxf(red[tid], red[tid + s]);
        __syncthreads();
    }
    float mx = red[0];
    __syncthreads();
    red[tid] = (tid < 100) ? expf(logits[tid] - mx) : 0.0f;
    __syncthreads();
    for (int s = 128; s > 0; s >>= 1) {
        if (tid < s) red[tid] += red[tid + s];
        __syncthreads();
    }
    float lse = logf(red[0]);
    if (tid < 100) out[g * 100 + tid] = logits[tid] - mx - lse;
}

// plain FC + relu (fallback path)
__global__ void k_fc(const float* __restrict__ in, const float* __restrict__ W,
                     const float* __restrict__ bias, float* out, int fi, int fo) {
    __shared__ float row[512];
    int g = blockIdx.x, tid = threadIdx.x;
    for (int k = tid; k < fi; k += blockDim.x) row[k] = in[g * fi + k];
    __syncthreads();
    if (tid < fo) {
        float acc = bias[tid];
        for (int k = 0; k < fi; ++k) acc += row[k] * W[k * fo + tid];
        out[g * fo + tid] = acc > 0.0f ? acc : 0.0f;
    }
}

// fallback FC2+FC3+log_softmax
__global__ __launch_bounds__(256) void k_fc23(const float* __restrict__ t1,
                                              const float* __restrict__ fw2,
                                              const float* __restrict__ fb2,
                                              const float* __restrict__ fw3,
                                              const float* __restrict__ fb3,
                                              float* __restrict__ out) {
    __shared__ float row[256];
    __shared__ float t2s[256];
    __shared__ float red[256];
    __shared__ float logits[100];
    const int g = blockIdx.x, tid = threadIdx.x;
    row[tid] = t1[g * 256 + tid];
    __syncthreads();
    float acc = fb2[tid];
    for (int k = 0; k < 256; ++k) acc += row[k] * fw2[k * 256 + tid];
    t2s[tid] = acc > 0.0f ? acc : 0.0f;
    __syncthreads();
    float v = -INFINITY;
    if (tid < 100) {
        float a3 = fb3[tid];
        for (int k = 0; k < 256; ++k) a3 += t2s[k] * fw3[k * 100 + tid];
        logits[tid] = a3;
        v = a3;
    }
    red[tid] = v;
    __syncthreads();
    for (int s = 128; s > 0; s >>= 1) {
        if (tid < s) red[tid] = fmaxf(red[tid], red[tid + s]);
        __syncthreads();
    }
    float mx = red[0];
    __syncthreads();
    red[tid] = (tid < 100) ? expf(logits[tid] - mx) : 0.0f;
    __syncthreads();
    for (int s = 128; s > 0; s >>= 1) {
        if (tid < s) red[tid] += red[tid + s];
        __syncthreads();
    }
    float lse = logf(red[0]);
    if (tid < 100) out[g * 100 + tid] = logits[tid] - mx - lse;
}

// ---------------- launch ----------------
extern "C" void kernel_launch(void* const* d_in, const int* in_sizes, int n_in,
                              void* d_out, int out_size, void* d_ws, size_t ws_size,
                              hipStream_t stream) {
    const float* pos = (const float*)d_in[0];
    const int* ei = (const int*)d_in[1];
    const float* p = (const float*)d_in[3];
    const float *W[5], *bb[5], *gg[5], *be[5];
    for (int i = 0; i < 5; ++i) {
        W[i]  = (const float*)d_in[4 + 4 * i];
        bb[i] = (const float*)d_in[5 + 4 * i];
        gg[i] = (const float*)d_in[6 + 4 * i];
        be[i] = (const float*)d_in[7 + 4 * i];
    }
    const float* fw1 = (const float*)d_in[24]; const float* fb1 = (const float*)d_in[25];
    const float* fw2 = (const float*)d_in[26]; const float* fb2 = (const float*)d_in[27];
    const float* fw3 = (const float*)d_in[28]; const float* fb3 = (const float*)d_in[29];
    float* out = (float*)d_out;

    const int fins[5]  = {3, 64, 128, 128, 256};
    const int kpads[5] = {32, 64, 128, 128, 256};
    const int fouts[5] = {64, 128, 128, 256, 512};

    size_t off = 0;
    char* base = (char*)d_ws;
    auto alloc = [&](size_t bytes) { char* q = base + off; off += (bytes + 255) & ~(size_t)255; return q; };

    float* Y      = (float*)alloc((size_t)NN * 512 * 4);
    float* Hf     = (float*)alloc((size_t)NN * 512 * 4);   // f32 fallback H; bf16 Hb aliases
    int*   remap  = (int*)alloc((size_t)NTOT * 4);
    int*   deg    = (int*)alloc(NN * 4);
    int*   cursor = (int*)alloc(NN * 4);
    int*   rowptr = (int*)alloc((NN + 1) * 4);
    int*   ecol   = (int*)alloc((size_t)NE * 4);
    float* ew     = (float*)alloc((size_t)NE * 4);
    float* psum   = (float*)alloc((size_t)BN1_CHUNKS * 512 * 4);
    float* psq    = (float*)alloc((size_t)BN1_CHUNKS * 512 * 4);
    float* scale  = (float*)alloc(512 * 4);
    float* shift  = (float*)alloc(512 * 4);
    float* pooled = (float*)alloc(8 * 512 * 4);
    float* t1     = (float*)alloc(8 * 256 * 4);
    unsigned short* Ab0 = (unsigned short*)alloc((size_t)NN * 32 * 2);
    float* part   = (float*)alloc((size_t)256 * 512 * 4);
    float* part2  = (float*)alloc((size_t)8 * 16 * 256 * 4);
    float* part3  = (float*)alloc((size_t)8 * 8 * 256 * 4);
    unsigned short* WT[5];
    for (int l = 0; l < 5; ++l) WT[l] = (unsigned short*)alloc((size_t)fouts[l] * kpads[l] * 2);
    unsigned short* Hb = (unsigned short*)Hf;
    const bool mfma = (ws_size >= off);

    k_topk2<<<BGR, 1024, 0, stream>>>(pos, p, remap, Y, Ab0, deg, cursor);
    k_deg<<<NE / 256, 256, 0, stream>>>(ei, remap, deg);
    k_scan<<<1, 1024, 0, stream>>>(deg, rowptr);
    k_place2<<<NE / 256, 256, 0, stream>>>(ei, remap, deg, rowptr, cursor, ecol, ew);

    if (mfma) {
        k_wt_all<<<(190464 + 255) / 256, 256, 0, stream>>>(W[0], W[1], W[2], W[3], W[4],
                                                           WT[0], WT[1], WT[2], WT[3], WT[4]);
        for (int l = 0; l < 5; ++l) {
            int fo = fouts[l];
            if (l == 0) {
                dim3 mg(NN / 64, fo / 64);
                k_mm2<<<mg, 256, 0, stream>>>(Ab0, nullptr, nullptr, nullptr,
                                              WT[l], Hb, kpads[l], fo);
            } else if (fo == 512) {
                dim3 mg(NN / 64, fo / 128);
                k_mm2w<<<mg, 256, 0, stream>>>(Y, scale, shift, WT[l], Hb, kpads[l], fo);
            } else {
                dim3 mg(NN / 64, fo / 64);
                k_mm2<<<mg, 256, 0, stream>>>(nullptr, Y, scale, shift,
                                              WT[l], Hb, kpads[l], fo);
            }
            int cbs = (fo < 128) ? 1 : fo / 128;
            k_gfuse<<<BN1_CHUNKS * cbs, 256, 0, stream>>>(Hb, nullptr, rowptr, ecol, ew,
                                                          deg, bb[l], Y, psum, psq, fo);
            k_bn2p<<<fo, 256, 0, stream>>>(psum, psq, gg[l], be[l], scale, shift, fo);
        }
        k_pool_af<<<256, 256, 0, stream>>>(Y, scale, shift, part);
        k_fc1s<<<dim3(8, 16), 256, 0, stream>>>(part, fw1, part2);
        k_fc2s<<<dim3(8, 8), 256, 0, stream>>>(part2, fb1, fw2, part3);
        k_fc3f<<<8, 256, 0, stream>>>(part3, fb2, fw3, fb3, out);
    } else {
        for (int l = 0; l < 5; ++l) {
            int fi = fins[l], fo = fouts[l];
            dim3 mg(NN / BM, fo / BNT);
            k_mm<<<mg, 256, 0, stream>>>(Y, W[l], Hf, fi, fo);
            int cbs = (fo < 128) ? 1 : fo / 128;
            k_gfuse<<<BN1_CHUNKS * cbs, 256, 0, stream>>>(nullptr, Hf, rowptr, ecol, ew,
                                                          deg, bb[l], Y, psum, psq, fo);
            k_bn2p<<<fo, 256, 0, stream>>>(psum, psq, gg[l], be[l], scale, shift, fo);
            k_bnapply<<<(NN * fo) / 1024, 256, 0, stream>>>(Y, scale, shift, fo);
        }
        k_pool<<<64, 256, 0, stream>>>(Y, pooled);
        k_fc<<<8, 256, 0, stream>>>(pooled, fw1, fb1, t1, 512, 256);
        k_fc23<<<8, 256, 0, stream>>>(t1, fw2, fb2, fw3, fb3, out);
    }
}